// Round 5
// baseline (1304.099 us; speedup 1.0000x reference)
//
#include <hip/hip_runtime.h>
#include <hip/hip_cooperative_groups.h>
#include <math.h>

namespace cg = cooperative_groups;

#define NN 50000
#define EE 800000
#define BBG 256
#define HHC 128
#define SEG_CAP 240
#define NBIN 196   // coarse bins of 256 nodes
#define NBLK 196   // blocks in K1/K3 (4096 edges each)

__device__ __forceinline__ float4 aff4(float4 v, float4 sc, float4 sh) {
  v.x = fmaxf(fmaf(v.x, sc.x, sh.x), 0.f);
  v.y = fmaxf(fmaf(v.y, sc.y, sh.y), 0.f);
  v.z = fmaxf(fmaf(v.z, sc.z, sh.z), 0.f);
  v.w = fmaxf(fmaf(v.w, sc.w, sh.w), 0.f);
  return v;
}
__device__ __forceinline__ void add4(float4& a, float4 b) {
  a.x += b.x; a.y += b.y; a.z += b.z; a.w += b.w;
}

// ---------------- utility ----------------

__global__ void zero4_kernel(float4* p, int n) {
  int i = blockIdx.x * 256 + threadIdx.x;
  if (i < n) p[i] = make_float4(0.f, 0.f, 0.f, 0.f);
}

// batch is sorted: gptr[g] = first index with batch >= g; gptr[256] = NN
__global__ void gptr_boundary_kernel(const int* __restrict__ batch, int* __restrict__ gptr) {
  int i = blockIdx.x * 256 + threadIdx.x;
  if (i >= NN) return;
  int b = batch[i];
  int prev = (i == 0) ? -1 : batch[i - 1];
  for (int g = prev + 1; g <= b; ++g) gptr[g] = i;
  if (i == NN - 1) {
    for (int g = b + 1; g <= BBG; ++g) gptr[g] = NN;
  }
}

// ---- atomic-free CSR build (two-level counting sort) ----

__global__ __launch_bounds__(256) void coarse_hist_kernel(const int* __restrict__ ei,
                                                          int* __restrict__ partial) {
  __shared__ int hist[NBIN];
  int tid = threadIdx.x, b = blockIdx.x;
  if (tid < NBIN) hist[tid] = 0;
  __syncthreads();
  const int4* dst4 = (const int4*)(ei + EE);
#pragma unroll
  for (int c = 0; c < 4; ++c) {
    int idx = b * 1024 + c * 256 + tid;
    if (idx < EE / 4) {
      int4 d = dst4[idx];
      atomicAdd(&hist[d.x >> 8], 1);
      atomicAdd(&hist[d.y >> 8], 1);
      atomicAdd(&hist[d.z >> 8], 1);
      atomicAdd(&hist[d.w >> 8], 1);
    }
  }
  __syncthreads();
  if (tid < NBIN) partial[tid * NBLK + b] = hist[tid];
}

__global__ void scan_partials_kernel(const int* __restrict__ partial,
                                     int* __restrict__ block_base, int* __restrict__ total) {
  __shared__ int buf[256];
  int bin = blockIdx.x, tid = threadIdx.x;
  int v = (tid < NBLK) ? partial[bin * NBLK + tid] : 0;
  buf[tid] = v;
  __syncthreads();
  for (int off = 1; off < 256; off <<= 1) {
    int t = (tid >= off) ? buf[tid - off] : 0;
    __syncthreads();
    buf[tid] += t;
    __syncthreads();
  }
  if (tid < NBLK) block_base[bin * NBLK + tid] = buf[tid] - v;
  if (tid == 255) total[bin] = buf[255];
}

__global__ void scan_totals_kernel(const int* __restrict__ total, int* __restrict__ coarse_base) {
  __shared__ int buf[256];
  int tid = threadIdx.x;
  int v = (tid < NBIN) ? total[tid] : 0;
  buf[tid] = v;
  __syncthreads();
  for (int off = 1; off < 256; off <<= 1) {
    int t = (tid >= off) ? buf[tid - off] : 0;
    __syncthreads();
    buf[tid] += t;
    __syncthreads();
  }
  if (tid < NBIN) coarse_base[tid] = buf[tid] - v;
  if (tid == 255) coarse_base[NBIN] = buf[255];
}

__global__ __launch_bounds__(256) void bucket_scatter_kernel(const int* __restrict__ ei,
                                                             const int* __restrict__ coarse_base,
                                                             const int* __restrict__ block_base,
                                                             int* __restrict__ packed) {
  __shared__ int cursor[NBIN];
  int tid = threadIdx.x, b = blockIdx.x;
  if (tid < NBIN) cursor[tid] = coarse_base[tid] + block_base[tid * NBLK + b];
  __syncthreads();
  const int4* src4 = (const int4*)ei;
  const int4* dst4 = (const int4*)(ei + EE);
#pragma unroll
  for (int c = 0; c < 4; ++c) {
    int idx = b * 1024 + c * 256 + tid;
    if (idx < EE / 4) {
      int4 s = src4[idx];
      int4 d = dst4[idx];
      int p;
      p = atomicAdd(&cursor[d.x >> 8], 1); packed[p] = (s.x << 8) | (d.x & 255);
      p = atomicAdd(&cursor[d.y >> 8], 1); packed[p] = (s.y << 8) | (d.y & 255);
      p = atomicAdd(&cursor[d.z >> 8], 1); packed[p] = (s.z << 8) | (d.z & 255);
      p = atomicAdd(&cursor[d.w >> 8], 1); packed[p] = (s.w << 8) | (d.w & 255);
    }
  }
}

__global__ __launch_bounds__(256) void csr_finalize_kernel(const int* __restrict__ packed,
                                                           const int* __restrict__ coarse_base,
                                                           int* __restrict__ row_start,
                                                           int* __restrict__ csr) {
  __shared__ int fh[256];
  __shared__ int fb[256];
  int bin = blockIdx.x, tid = threadIdx.x;
  int e0 = coarse_base[bin], e1 = coarse_base[bin + 1];
  fh[tid] = 0;
  __syncthreads();
  for (int e = e0 + tid; e < e1; e += 256) atomicAdd(&fh[packed[e] & 255], 1);
  __syncthreads();
  int v = fh[tid];
  fb[tid] = v;
  __syncthreads();
  for (int off = 1; off < 256; off <<= 1) {
    int t = (tid >= off) ? fb[tid - off] : 0;
    __syncthreads();
    fb[tid] += t;
    __syncthreads();
  }
  int excl = fb[tid] - v;
  int node = bin * 256 + tid;
  if (node < NN) row_start[node] = e0 + excl;
  if (bin == NBIN - 1 && tid == 0) row_start[NN] = EE;
  __syncthreads();
  fb[tid] = excl;  // cursor
  __syncthreads();
  for (int e = e0 + tid; e < e1; e += 256) {
    int p = packed[e];
    int pos = atomicAdd(&fb[p & 255], 1);
    csr[e0 + pos] = p >> 8;
  }
}

// ---------------- weight prep (single kernel) ----------------
__global__ void prep_weights_kernel(const float* __restrict__ W0, const float* __restrict__ W1,
                                    const float* __restrict__ W2, const float* __restrict__ W3,
                                    const float* __restrict__ Wih0, const float* __restrict__ Whh0,
                                    const float* __restrict__ WihR, const float* __restrict__ WhhR,
                                    const float* __restrict__ b0, const float* __restrict__ bR,
                                    float* __restrict__ ginWT, float* __restrict__ WT0,
                                    float* __restrict__ WTR, float* __restrict__ bc0,
                                    float* __restrict__ bcR) {
  int idx = blockIdx.x * 256 + threadIdx.x;  // grid 2568*256 = 657408 exact
  if (idx < 65536) {
    int m = idx >> 14;
    int r = idx & 16383;
    int k = r >> 7, o = r & 127;
    const float* W = (m == 0) ? W0 : (m == 1) ? W1 : (m == 2) ? W2 : W3;
    ginWT[idx] = W[o * 128 + k];
  } else if (idx < 262144) {
    int t = idx - 65536;
    int k = t >> 9, op = t & 511;
    int j = op >> 2, g = op & 3;
    int row = g * 128 + j;
    WT0[t] = (k < 256) ? Wih0[row * 256 + k] : Whh0[row * 128 + (k - 256)];
  } else if (idx < 655360) {
    int t = idx - 262144;
    int l = t >> 17;
    int rem = t & 131071;
    int k = rem >> 9, op = rem & 511;
    int j = op >> 2, g = op & 3;
    int row = g * 128 + j;
    WTR[t] = (k < 128) ? WihR[((size_t)l * 512 + row) * 128 + k]
                       : WhhR[((size_t)l * 512 + row) * 128 + (k - 128)];
  } else {
    int t = idx - 655360;
    if (t < 512) {
      bc0[t] = b0[(t & 3) * 128 + (t >> 2)];
    } else {
      int u = t - 512;
      int l = u >> 9, op = u & 511;
      bcR[u] = bR[l * 512 + (op & 3) * 128 + (op >> 2)];
    }
  }
}

// ---------------- GIN ----------------

// one wave per node; each 32-lane half loads a full 512B row as float4 ->
// 2 edges per load instruction, 16 edges (8KB) in flight per wave.
template <bool AFF>
__global__ __launch_bounds__(256) void gin_agg_kernel(
    const float* __restrict__ xin, const int* __restrict__ row_start,
    const int* __restrict__ csr,
    const float* __restrict__ stats, const float* __restrict__ gamma,
    const float* __restrict__ beta, float* __restrict__ outp) {
  __shared__ float sc_s[128], sh_s[128];
  if (AFF) {
    int t = threadIdx.x;
    if (t < 128) {
      const float invN = 1.0f / (float)NN;
      float mm = stats[t] * invN;
      float vv = stats[128 + t] * invN - mm * mm;
      float rs = rsqrtf(vv + 1e-5f);
      float sc = gamma[t] * rs;
      sc_s[t] = sc;
      sh_s[t] = beta[t] - mm * sc;
    }
    __syncthreads();
  }
  int node = blockIdx.x * 4 + (threadIdx.x >> 6);  // exact: 12500*4 = 50000
  int lane = threadIdx.x & 63;
  int half = lane >> 5, ln = lane & 31;
  const float4* x4 = (const float4*)xin;
  float4 sc4 = make_float4(0.f, 0.f, 0.f, 0.f), sh4 = sc4;
  if (AFF) {
    sc4 = *(const float4*)&sc_s[4 * ln];
    sh4 = *(const float4*)&sh_s[4 * ln];
  }
  int s0 = row_start[node], s1 = row_start[node + 1];
  float4 self = x4[(size_t)node * 32 + ln];
  if (AFF) self = aff4(self, sc4, sh4);
  float4 c0 = make_float4(0.f, 0.f, 0.f, 0.f), c1 = c0, c2 = c0, c3 = c0;
  int cnt = s1 - s0;
  int mainEnd = s0 + (cnt & ~15);
  for (int j = s0; j < mainEnd; j += 16) {
    int i0 = csr[j + half + 0];
    int i1 = csr[j + half + 2];
    int i2 = csr[j + half + 4];
    int i3 = csr[j + half + 6];
    int i4 = csr[j + half + 8];
    int i5 = csr[j + half + 10];
    int i6 = csr[j + half + 12];
    int i7 = csr[j + half + 14];
    float4 v0 = x4[(size_t)i0 * 32 + ln];
    float4 v1 = x4[(size_t)i1 * 32 + ln];
    float4 v2 = x4[(size_t)i2 * 32 + ln];
    float4 v3 = x4[(size_t)i3 * 32 + ln];
    float4 v4 = x4[(size_t)i4 * 32 + ln];
    float4 v5 = x4[(size_t)i5 * 32 + ln];
    float4 v6 = x4[(size_t)i6 * 32 + ln];
    float4 v7 = x4[(size_t)i7 * 32 + ln];
    if (AFF) {
      v0 = aff4(v0, sc4, sh4); v1 = aff4(v1, sc4, sh4);
      v2 = aff4(v2, sc4, sh4); v3 = aff4(v3, sc4, sh4);
      v4 = aff4(v4, sc4, sh4); v5 = aff4(v5, sc4, sh4);
      v6 = aff4(v6, sc4, sh4); v7 = aff4(v7, sc4, sh4);
    }
    add4(c0, v0); add4(c1, v1); add4(c2, v2); add4(c3, v3);
    add4(c0, v4); add4(c1, v5); add4(c2, v6); add4(c3, v7);
  }
  for (int j = mainEnd + half; j < s1; j += 2) {
    int i = csr[j];
    float4 v = x4[(size_t)i * 32 + ln];
    if (AFF) v = aff4(v, sc4, sh4);
    add4(c0, v);
  }
  float4 t;
  t.x = (c0.x + c1.x) + (c2.x + c3.x);
  t.y = (c0.y + c1.y) + (c2.y + c3.y);
  t.z = (c0.z + c1.z) + (c2.z + c3.z);
  t.w = (c0.w + c1.w) + (c2.w + c3.w);
  t.x += __shfl_xor(t.x, 32);
  t.y += __shfl_xor(t.y, 32);
  t.z += __shfl_xor(t.z, 32);
  t.w += __shfl_xor(t.w, 32);
  t.x += self.x; t.y += self.y; t.z += self.z; t.w += self.w;
  if (half == 0) ((float4*)outp)[(size_t)node * 32 + ln] = t;
}

// C = f(A) @ W^T + b, f = optional fused BN(stats)+relu; per-channel stats atomics.
template <bool BN>
__global__ __launch_bounds__(256) void gemm_gin_kernel(
    const float* __restrict__ A, const float* __restrict__ WT,
    const float* __restrict__ bias,
    const float* __restrict__ stats, const float* __restrict__ gamma,
    const float* __restrict__ beta,
    float* __restrict__ C,
    float* __restrict__ ssum, float* __restrict__ ssq, int M) {
  __shared__ float As[64][132];
  __shared__ float Wt[128][68];
  __shared__ float bsc[128], bsh[128];
  int tid = threadIdx.x;
  if (BN) {
    if (tid < 128) {
      const float invN = 1.0f / (float)NN;
      float mm = stats[tid] * invN;
      float vv = stats[128 + tid] * invN - mm * mm;
      float rs = rsqrtf(vv + 1e-5f);
      float sc = gamma[tid] * rs;
      bsc[tid] = sc;
      bsh[tid] = beta[tid] - mm * sc;
    }
    __syncthreads();
  }
  int tx = tid & 15, ty = tid >> 4;
  int bx = blockIdx.x & 1, by = blockIdx.x >> 1;
  int row0 = by * 64, c0 = bx * 64;
#pragma unroll
  for (int i = 0; i < 8; ++i) {
    int slot = tid + i * 256;
    int r = slot >> 5, k4 = (slot & 31) << 2;
    float4 v = make_float4(0.f, 0.f, 0.f, 0.f);
    if (row0 + r < M) v = *(const float4*)(A + (size_t)(row0 + r) * 128 + k4);
    if (BN) {
      v.x = fmaxf(fmaf(v.x, bsc[k4 + 0], bsh[k4 + 0]), 0.f);
      v.y = fmaxf(fmaf(v.y, bsc[k4 + 1], bsh[k4 + 1]), 0.f);
      v.z = fmaxf(fmaf(v.z, bsc[k4 + 2], bsh[k4 + 2]), 0.f);
      v.w = fmaxf(fmaf(v.w, bsc[k4 + 3], bsh[k4 + 3]), 0.f);
    }
    *(float4*)&As[r][k4] = v;
  }
#pragma unroll
  for (int i = 0; i < 8; ++i) {
    int slot = tid + i * 256;
    int k = slot >> 4, c4 = (slot & 15) << 2;
    *(float4*)&Wt[k][c4] = *(const float4*)(WT + (size_t)k * 128 + c0 + c4);
  }
  __syncthreads();
  float acc[4][4];
#pragma unroll
  for (int i = 0; i < 4; ++i)
#pragma unroll
    for (int j = 0; j < 4; ++j) acc[i][j] = 0.f;
#pragma unroll 4
  for (int kk = 0; kk < 128; kk += 4) {
    float4 w0 = *(const float4*)&Wt[kk + 0][tx << 2];
    float4 w1 = *(const float4*)&Wt[kk + 1][tx << 2];
    float4 w2 = *(const float4*)&Wt[kk + 2][tx << 2];
    float4 w3 = *(const float4*)&Wt[kk + 3][tx << 2];
#pragma unroll
    for (int i = 0; i < 4; ++i) {
      float4 a = *(const float4*)&As[(ty << 2) + i][kk];
      acc[i][0] += a.x * w0.x + a.y * w1.x + a.z * w2.x + a.w * w3.x;
      acc[i][1] += a.x * w0.y + a.y * w1.y + a.z * w2.y + a.w * w3.y;
      acc[i][2] += a.x * w0.z + a.y * w1.z + a.z * w2.z + a.w * w3.z;
      acc[i][3] += a.x * w0.w + a.y * w1.w + a.z * w2.w + a.w * w3.w;
    }
  }
  __syncthreads();
  float b0v = bias[c0 + (tx << 2) + 0];
  float b1v = bias[c0 + (tx << 2) + 1];
  float b2v = bias[c0 + (tx << 2) + 2];
  float b3v = bias[c0 + (tx << 2) + 3];
  float psum[4] = {0.f, 0.f, 0.f, 0.f}, psq[4] = {0.f, 0.f, 0.f, 0.f};
#pragma unroll
  for (int i = 0; i < 4; ++i) {
    int r = row0 + (ty << 2) + i;
    if (r < M) {
      float4 v;
      v.x = acc[i][0] + b0v; v.y = acc[i][1] + b1v;
      v.z = acc[i][2] + b2v; v.w = acc[i][3] + b3v;
      *(float4*)(C + (size_t)r * 128 + c0 + (tx << 2)) = v;
      psum[0] += v.x; psum[1] += v.y; psum[2] += v.z; psum[3] += v.w;
      psq[0] += v.x * v.x; psq[1] += v.y * v.y; psq[2] += v.z * v.z; psq[3] += v.w * v.w;
    }
  }
  float* red = &As[0][0];
#pragma unroll
  for (int j = 0; j < 4; ++j) {
    red[ty * 68 + (tx << 2) + j] = psum[j];
    red[1088 + ty * 68 + (tx << 2) + j] = psq[j];
  }
  __syncthreads();
  if (tid < 64) {
    float s = 0.f, sq = 0.f;
#pragma unroll
    for (int t = 0; t < 16; ++t) { s += red[t * 68 + tid]; sq += red[1088 + t * 68 + tid]; }
    atomicAdd(&ssum[c0 + tid], s);
    atomicAdd(&ssq[c0 + tid], sq);
  }
}

// ---------------- fused Set2Set (cooperative) ----------------
// grid 256x256, 1 block/CU. 4 steps x (4 LSTM cells + attention), 19 grid syncs.
// LSTM phases use blocks 0..127 (bx=blk&7 col-group, by=blk>>3 row-group).
// Attention phase: block g = graph g; BN4 affine+relu fused into x reads.
__global__ void __launch_bounds__(256) set2set_kernel(
    const float* __restrict__ x, const int* __restrict__ gptr,
    const float* __restrict__ stats, const float* __restrict__ gamma,
    const float* __restrict__ beta,
    const float* __restrict__ WT0, const float* __restrict__ WTR,
    const float* __restrict__ bc0, const float* __restrict__ bcR,
    float* __restrict__ cbuf, float* __restrict__ hbuf,
    float* __restrict__ qstar, float* __restrict__ ebuf,
    const float* __restrict__ linW, const float* __restrict__ linb,
    float* __restrict__ out) {
  cg::grid_group grid = cg::this_grid();
  __shared__ __align__(16) char smem[127456];
  // LSTM-phase layout
  float* As = (float*)smem;                // [16][132]
  float* Wt = (float*)(smem + 8448);       // [128][68]
  // attention-phase layout (time-disjoint with LSTM layout)
  float* xs = (float*)smem;                // [SEG_CAP*128]
  float* es_s = (float*)(smem + 122880);   // [SEG_CAP]
  float* q_s = (float*)(smem + 123840);    // [128]
  float* wred = (float*)(smem + 124352);   // [4]
  float* rpart = (float*)(smem + 124368);  // [4][128]
  float* bsc = (float*)(smem + 126416);    // [128]
  float* bsh = (float*)(smem + 126928);    // [128]
  float* sm2 = (float*)(smem + 127440);    // [2]: max, sum

  int blk = blockIdx.x, tid = threadIdx.x;
  int g = blk;
  int lane = tid & 63, w = tid >> 6;
  int tx = tid & 15, ty = tid >> 4;
  int bx = blk & 7, by = blk >> 3;

  for (int step = 0; step < 4; ++step) {
    int rp = step & 1, wp = 1 - rp;
    // ---- 4 stacked LSTM cells ----
    for (int cell = 0; cell < 4; ++cell) {
      if (blk < 128) {
        const float* inA; int pitchA, splitK, K;
        const float* inB; const float* WTc; const float* bias;
        float* cst; float* hw;
        if (cell == 0) {
          inA = qstar; pitchA = 256; splitK = 256; K = 384;
          inB = hbuf + (size_t)(0 * 2 + rp) * 32768;
          WTc = WT0; bias = bc0; cst = cbuf;
          hw = hbuf + (size_t)(0 * 2 + wp) * 32768;
        } else {
          inA = hbuf + (size_t)((cell - 1) * 2 + wp) * 32768;
          pitchA = 128; splitK = 128; K = 256;
          inB = hbuf + (size_t)(cell * 2 + rp) * 32768;
          WTc = WTR + (size_t)(cell - 1) * 131072;
          bias = bcR + (cell - 1) * 512;
          cst = cbuf + (size_t)cell * 32768;
          hw = hbuf + (size_t)(cell * 2 + wp) * 32768;
        }
        int row0 = by * 16, c0 = bx * 64;
        float a0 = 0.f, a1 = 0.f, a2 = 0.f, a3 = 0.f;
        for (int kc = 0; kc < K; kc += 128) {
#pragma unroll
          for (int i = 0; i < 2; ++i) {
            int slot = tid + i * 256;
            int r = slot >> 5, k4 = (slot & 31) << 2;
            int gc = kc + k4;
            const float* src = (gc < splitK) ? inA + (size_t)(row0 + r) * pitchA + gc
                                             : inB + (size_t)(row0 + r) * 128 + (gc - splitK);
            *(float4*)&As[r * 132 + k4] = *(const float4*)src;
          }
#pragma unroll
          for (int i = 0; i < 8; ++i) {
            int slot = tid + i * 256;
            int k = slot >> 4, c4 = (slot & 15) << 2;
            *(float4*)&Wt[k * 68 + c4] = *(const float4*)(WTc + (size_t)(kc + k) * 512 + c0 + c4);
          }
          __syncthreads();
#pragma unroll 4
          for (int kk = 0; kk < 128; kk += 4) {
            float4 a = *(const float4*)&As[ty * 132 + kk];
            float4 w0 = *(const float4*)&Wt[(kk + 0) * 68 + (tx << 2)];
            float4 w1 = *(const float4*)&Wt[(kk + 1) * 68 + (tx << 2)];
            float4 w2 = *(const float4*)&Wt[(kk + 2) * 68 + (tx << 2)];
            float4 w3 = *(const float4*)&Wt[(kk + 3) * 68 + (tx << 2)];
            a0 += a.x * w0.x + a.y * w1.x + a.z * w2.x + a.w * w3.x;
            a1 += a.x * w0.y + a.y * w1.y + a.z * w2.y + a.w * w3.y;
            a2 += a.x * w0.z + a.y * w1.z + a.z * w2.z + a.w * w3.z;
            a3 += a.x * w0.w + a.y * w1.w + a.z * w2.w + a.w * w3.w;
          }
          __syncthreads();
        }
        int b = row0 + ty;
        int j = bx * 16 + tx;
        int ob = c0 + (tx << 2);
        float ii = a0 + bias[ob + 0];
        float ff = a1 + bias[ob + 1];
        float gg = a2 + bias[ob + 2];
        float oo = a3 + bias[ob + 3];
        float cp = cst[b * 128 + j];
        float si = 1.f / (1.f + expf(-ii));
        float sf = 1.f / (1.f + expf(-ff));
        float so = 1.f / (1.f + expf(-oo));
        float cn = sf * cp + si * tanhf(gg);
        float hv = so * tanhf(cn);
        cst[b * 128 + j] = cn;
        hw[b * 128 + j] = hv;
      }
      grid.sync();
    }
    // ---- attention (BN4 fused) ----
    {
      const float* h3 = hbuf + (size_t)(3 * 2 + wp) * 32768;
      if (tid < 128) {
        const float invN = 1.0f / (float)NN;
        float mm = stats[tid] * invN;
        float vv = stats[128 + tid] * invN - mm * mm;
        float rs = rsqrtf(vv + 1e-5f);
        float sc = gamma[tid] * rs;
        bsc[tid] = sc;
        bsh[tid] = beta[tid] - mm * sc;
        q_s[tid] = h3[g * 128 + tid];
      }
      __syncthreads();
      int s0 = gptr[g], s1 = gptr[g + 1];
      bool fit = (s1 - s0) <= SEG_CAP;
      const float2* x2 = (const float2*)x;
      float qx = q_s[2 * lane], qy = q_s[2 * lane + 1];
      float sc0 = bsc[2 * lane], sc1 = bsc[2 * lane + 1];
      float sh0 = bsh[2 * lane], sh1 = bsh[2 * lane + 1];
      // pass 1: e + max (stage transformed x into LDS)
      float wmax = -3.0e38f;
      for (int n = s0 + w; n < s1; n += 4) {
        float2 v = x2[(size_t)n * 64 + lane];
        v.x = fmaxf(fmaf(v.x, sc0, sh0), 0.f);
        v.y = fmaxf(fmaf(v.y, sc1, sh1), 0.f);
        if (fit) {
          xs[(n - s0) * 128 + 2 * lane] = v.x;
          xs[(n - s0) * 128 + 2 * lane + 1] = v.y;
        }
        float e = v.x * qx + v.y * qy;
#pragma unroll
        for (int sh = 32; sh; sh >>= 1) e += __shfl_xor(e, sh);
        if (lane == 0) { if (fit) es_s[n - s0] = e; else ebuf[n] = e; }
        wmax = fmaxf(wmax, e);
      }
      if (lane == 0) wred[w] = wmax;
      __syncthreads();
      if (tid == 0) sm2[0] = fmaxf(fmaxf(wred[0], wred[1]), fmaxf(wred[2], wred[3]));
      __syncthreads();
      float m = sm2[0];
      // pass 2: sum exp
      float loc = 0.f;
      for (int n = s0 + tid; n < s1; n += 256) {
        float e = fit ? es_s[n - s0] : ebuf[n];
        loc += expf(e - m);
      }
#pragma unroll
      for (int sh = 32; sh; sh >>= 1) loc += __shfl_xor(loc, sh);
      __syncthreads();
      if (lane == 0) wred[w] = loc;
      __syncthreads();
      if (tid == 0) sm2[1] = wred[0] + wred[1] + wred[2] + wred[3];
      __syncthreads();
      float inv = 1.0f / sm2[1];
      // pass 3: r = sum a*x
      float rx = 0.f, ry = 0.f;
      for (int n = s0 + w; n < s1; n += 4) {
        float e = fit ? es_s[n - s0] : ebuf[n];
        float coef = expf(e - m) * inv;
        float vx, vy;
        if (fit) {
          vx = xs[(n - s0) * 128 + 2 * lane];
          vy = xs[(n - s0) * 128 + 2 * lane + 1];
        } else {
          float2 v = x2[(size_t)n * 64 + lane];
          vx = fmaxf(fmaf(v.x, sc0, sh0), 0.f);
          vy = fmaxf(fmaf(v.y, sc1, sh1), 0.f);
        }
        rx += coef * vx; ry += coef * vy;
      }
      rpart[w * 128 + 2 * lane] = rx;
      rpart[w * 128 + 2 * lane + 1] = ry;
      __syncthreads();
      if (tid < 128) {
        float r = rpart[0 * 128 + tid] + rpart[1 * 128 + tid] +
                  rpart[2 * 128 + tid] + rpart[3 * 128 + tid];
        qstar[(size_t)g * 256 + tid] = q_s[tid];
        qstar[(size_t)g * 256 + 128 + tid] = r;
        es_s[tid] = r;
      }
      __syncthreads();
      if (step == 3) {
        float val = (tid < 128) ? q_s[tid] : es_s[tid - 128];
        float p0 = val * linW[tid];
        float p1 = val * linW[256 + tid];
#pragma unroll
        for (int sh = 32; sh; sh >>= 1) { p0 += __shfl_xor(p0, sh); p1 += __shfl_xor(p1, sh); }
        if (lane == 0) { wred[w] = p0; rpart[w] = p1; }
        __syncthreads();
        if (tid == 0) out[2 * g + 0] = wred[0] + wred[1] + wred[2] + wred[3] + linb[0];
        if (tid == 1) out[2 * g + 1] = rpart[0] + rpart[1] + rpart[2] + rpart[3] + linb[1];
      }
    }
    if (step < 3) grid.sync();
  }
}

// ---------------- launch ----------------

extern "C" void kernel_launch(void* const* d_in, const int* in_sizes, int n_in,
                              void* d_out, int out_size, void* d_ws, size_t ws_size,
                              hipStream_t stream) {
  const float* x = (const float*)d_in[0];
  const int* ei = (const int*)d_in[1];
  const int* batch = (const int*)d_in[2];
  const float* gW[4]  = {(const float*)d_in[3],  (const float*)d_in[7],
                         (const float*)d_in[11], (const float*)d_in[15]};
  const float* gb[4]  = {(const float*)d_in[4],  (const float*)d_in[8],
                         (const float*)d_in[12], (const float*)d_in[16]};
  const float* gga[4] = {(const float*)d_in[5],  (const float*)d_in[9],
                         (const float*)d_in[13], (const float*)d_in[17]};
  const float* gbe[4] = {(const float*)d_in[6],  (const float*)d_in[10],
                         (const float*)d_in[14], (const float*)d_in[18]};
  const float* Wih0 = (const float*)d_in[19];
  const float* Whh0 = (const float*)d_in[20];
  const float* b0   = (const float*)d_in[21];
  const float* WihR = (const float*)d_in[22];
  const float* WhhR = (const float*)d_in[23];
  const float* bR   = (const float*)d_in[24];
  const float* linW = (const float*)d_in[25];
  const float* linb = (const float*)d_in[26];
  float* out = (float*)d_out;

  char* base = (char*)d_ws;
  size_t off = 0;
  auto allocf = [&](size_t n) { float* p = (float*)(base + off); off += n * sizeof(float); return p; };
  float* xa    = allocf(6400000);
  float* xb    = allocf(6400000);
  float* ginWT = allocf(65536);
  float* WT0   = allocf(196608);
  float* WTR   = allocf(393216);
  float* bc0   = allocf(512);
  float* bcR   = allocf(1536);
  float* ebuf  = allocf(50000);
  // ---- zero region (contiguous): 459776 floats = 114944 float4 ----
  float* stats = allocf(1024);     // 4 x (sum128|sq128)
  float* cbuf  = allocf(131072);   // 4 x 256x128
  float* hbuf  = allocf(262144);   // [4][2][256x128]
  float* qstar = allocf(65536);    // 256x256
  // ---- ints (all fully written before read; no zeroing needed) ----
  int* row_start = (int*)(base + off); off += 50004 * 4;
  int* gptr = (int*)(base + off); off += 260 * 4;
  int* csr = (int*)(base + off); off += 800000 * 4;
  int* packed = (int*)(base + off); off += 800000 * 4;
  int* partial = (int*)(base + off); off += NBIN * NBLK * 4;
  int* block_base = (int*)(base + off); off += NBIN * NBLK * 4;
  int* total = (int*)(base + off); off += 256 * 4;
  int* coarse_base = (int*)(base + off); off += 260 * 4;
  (void)ws_size; (void)in_sizes; (void)n_in; (void)out_size;

  // prep
  zero4_kernel<<<449, 256, 0, stream>>>((float4*)stats, 114944);
  gptr_boundary_kernel<<<196, 256, 0, stream>>>(batch, gptr);
  coarse_hist_kernel<<<NBLK, 256, 0, stream>>>(ei, partial);
  scan_partials_kernel<<<NBIN, 256, 0, stream>>>(partial, block_base, total);
  scan_totals_kernel<<<1, 256, 0, stream>>>(total, coarse_base);
  bucket_scatter_kernel<<<NBLK, 256, 0, stream>>>(ei, coarse_base, block_base, packed);
  csr_finalize_kernel<<<NBIN, 256, 0, stream>>>(packed, coarse_base, row_start, csr);
  prep_weights_kernel<<<2568, 256, 0, stream>>>(gW[0], gW[1], gW[2], gW[3], Wih0, Whh0,
                                                WihR, WhhR, b0, bR, ginWT, WT0, WTR, bc0, bcR);

  // GIN layer 1
  gin_agg_kernel<false><<<12500, 256, 0, stream>>>(x, row_start, csr,
                                                   nullptr, nullptr, nullptr, xb);
  gemm_gin_kernel<false><<<1564, 256, 0, stream>>>(xb, ginWT + 0 * 16384, gb[0],
                                                   nullptr, nullptr, nullptr,
                                                   xa, stats + 0, stats + 128, NN);
  gemm_gin_kernel<true><<<1564, 256, 0, stream>>>(xa, ginWT + 1 * 16384, gb[1],
                                                  stats + 0, gga[0], gbe[0],
                                                  xb, stats + 256, stats + 384, NN);
  // GIN layer 2 (BN2 finalize+affine+relu fused into the gather)
  gin_agg_kernel<true><<<12500, 256, 0, stream>>>(xb, row_start, csr,
                                                  stats + 256, gga[1], gbe[1], xa);
  gemm_gin_kernel<false><<<1564, 256, 0, stream>>>(xa, ginWT + 2 * 16384, gb[2],
                                                   nullptr, nullptr, nullptr,
                                                   xb, stats + 512, stats + 640, NN);
  gemm_gin_kernel<true><<<1564, 256, 0, stream>>>(xb, ginWT + 3 * 16384, gb[3],
                                                  stats + 512, gga[2], gbe[2],
                                                  xa, stats + 768, stats + 896, NN);
  // xa holds pre-BN4 features; BN4 fused into set2set attention reads

  // fused Set2Set (cooperative): 16 LSTM cells + 4 attentions + final linear
  {
    const float* a0 = xa; const int* a1 = gptr;
    const float* a2 = stats + 768; const float* a3 = gga[3]; const float* a4 = gbe[3];
    const float* a5 = WT0; const float* a6 = WTR;
    const float* a7 = bc0; const float* a8 = bcR;
    float* a9 = cbuf; float* a10 = hbuf; float* a11 = qstar; float* a12 = ebuf;
    const float* a13 = linW; const float* a14 = linb; float* a15 = out;
    void* cargs[] = {&a0, &a1, &a2, &a3, &a4, &a5, &a6, &a7, &a8,
                     &a9, &a10, &a11, &a12, &a13, &a14, &a15};
    hipLaunchCooperativeKernel(reinterpret_cast<void*>(set2set_kernel),
                               dim3(256), dim3(256), cargs, 0, stream);
  }
}

// Round 6
// 716.671 us; speedup vs baseline: 1.8197x; 1.8197x over previous
//
#include <hip/hip_runtime.h>
#include <math.h>

#define NN 50000
#define EE 800000
#define BBG 256
#define HHC 128
#define SEG_CAP 256
#define NBIN 196   // coarse bins of 256 nodes
#define NBLK 196   // blocks in K1/K3 (4096 edges each)

__device__ __forceinline__ float4 aff4(float4 v, float4 sc, float4 sh) {
  v.x = fmaxf(fmaf(v.x, sc.x, sh.x), 0.f);
  v.y = fmaxf(fmaf(v.y, sc.y, sh.y), 0.f);
  v.z = fmaxf(fmaf(v.z, sc.z, sh.z), 0.f);
  v.w = fmaxf(fmaf(v.w, sc.w, sh.w), 0.f);
  return v;
}
__device__ __forceinline__ void add4(float4& a, float4 b) {
  a.x += b.x; a.y += b.y; a.z += b.z; a.w += b.w;
}

// ---------------- utility ----------------

__global__ void zero4_kernel(float4* p, int n) {
  int i = blockIdx.x * 256 + threadIdx.x;
  if (i < n) p[i] = make_float4(0.f, 0.f, 0.f, 0.f);
}

// batch is sorted: gptr[g] = first index with batch >= g; gptr[256] = NN
__global__ void gptr_boundary_kernel(const int* __restrict__ batch, int* __restrict__ gptr) {
  int i = blockIdx.x * 256 + threadIdx.x;
  if (i >= NN) return;
  int b = batch[i];
  int prev = (i == 0) ? -1 : batch[i - 1];
  for (int g = prev + 1; g <= b; ++g) gptr[g] = i;
  if (i == NN - 1) {
    for (int g = b + 1; g <= BBG; ++g) gptr[g] = NN;
  }
}

// ---- atomic-free CSR build (two-level counting sort) ----

__global__ __launch_bounds__(256) void coarse_hist_kernel(const int* __restrict__ ei,
                                                          int* __restrict__ partial) {
  __shared__ int hist[NBIN];
  int tid = threadIdx.x, b = blockIdx.x;
  if (tid < NBIN) hist[tid] = 0;
  __syncthreads();
  const int4* dst4 = (const int4*)(ei + EE);
#pragma unroll
  for (int c = 0; c < 4; ++c) {
    int idx = b * 1024 + c * 256 + tid;
    if (idx < EE / 4) {
      int4 d = dst4[idx];
      atomicAdd(&hist[d.x >> 8], 1);
      atomicAdd(&hist[d.y >> 8], 1);
      atomicAdd(&hist[d.z >> 8], 1);
      atomicAdd(&hist[d.w >> 8], 1);
    }
  }
  __syncthreads();
  if (tid < NBIN) partial[tid * NBLK + b] = hist[tid];
}

__global__ void scan_partials_kernel(const int* __restrict__ partial,
                                     int* __restrict__ block_base, int* __restrict__ total) {
  __shared__ int buf[256];
  int bin = blockIdx.x, tid = threadIdx.x;
  int v = (tid < NBLK) ? partial[bin * NBLK + tid] : 0;
  buf[tid] = v;
  __syncthreads();
  for (int off = 1; off < 256; off <<= 1) {
    int t = (tid >= off) ? buf[tid - off] : 0;
    __syncthreads();
    buf[tid] += t;
    __syncthreads();
  }
  if (tid < NBLK) block_base[bin * NBLK + tid] = buf[tid] - v;
  if (tid == 255) total[bin] = buf[255];
}

__global__ void scan_totals_kernel(const int* __restrict__ total, int* __restrict__ coarse_base) {
  __shared__ int buf[256];
  int tid = threadIdx.x;
  int v = (tid < NBIN) ? total[tid] : 0;
  buf[tid] = v;
  __syncthreads();
  for (int off = 1; off < 256; off <<= 1) {
    int t = (tid >= off) ? buf[tid - off] : 0;
    __syncthreads();
    buf[tid] += t;
    __syncthreads();
  }
  if (tid < NBIN) coarse_base[tid] = buf[tid] - v;
  if (tid == 255) coarse_base[NBIN] = buf[255];
}

__global__ __launch_bounds__(256) void bucket_scatter_kernel(const int* __restrict__ ei,
                                                             const int* __restrict__ coarse_base,
                                                             const int* __restrict__ block_base,
                                                             int* __restrict__ packed) {
  __shared__ int cursor[NBIN];
  int tid = threadIdx.x, b = blockIdx.x;
  if (tid < NBIN) cursor[tid] = coarse_base[tid] + block_base[tid * NBLK + b];
  __syncthreads();
  const int4* src4 = (const int4*)ei;
  const int4* dst4 = (const int4*)(ei + EE);
#pragma unroll
  for (int c = 0; c < 4; ++c) {
    int idx = b * 1024 + c * 256 + tid;
    if (idx < EE / 4) {
      int4 s = src4[idx];
      int4 d = dst4[idx];
      int p;
      p = atomicAdd(&cursor[d.x >> 8], 1); packed[p] = (s.x << 8) | (d.x & 255);
      p = atomicAdd(&cursor[d.y >> 8], 1); packed[p] = (s.y << 8) | (d.y & 255);
      p = atomicAdd(&cursor[d.z >> 8], 1); packed[p] = (s.z << 8) | (d.z & 255);
      p = atomicAdd(&cursor[d.w >> 8], 1); packed[p] = (s.w << 8) | (d.w & 255);
    }
  }
}

__global__ __launch_bounds__(256) void csr_finalize_kernel(const int* __restrict__ packed,
                                                           const int* __restrict__ coarse_base,
                                                           int* __restrict__ row_start,
                                                           int* __restrict__ csr) {
  __shared__ int fh[256];
  __shared__ int fb[256];
  int bin = blockIdx.x, tid = threadIdx.x;
  int e0 = coarse_base[bin], e1 = coarse_base[bin + 1];
  fh[tid] = 0;
  __syncthreads();
  for (int e = e0 + tid; e < e1; e += 256) atomicAdd(&fh[packed[e] & 255], 1);
  __syncthreads();
  int v = fh[tid];
  fb[tid] = v;
  __syncthreads();
  for (int off = 1; off < 256; off <<= 1) {
    int t = (tid >= off) ? fb[tid - off] : 0;
    __syncthreads();
    fb[tid] += t;
    __syncthreads();
  }
  int excl = fb[tid] - v;
  int node = bin * 256 + tid;
  if (node < NN) row_start[node] = e0 + excl;
  if (bin == NBIN - 1 && tid == 0) row_start[NN] = EE;
  __syncthreads();
  fb[tid] = excl;  // cursor
  __syncthreads();
  for (int e = e0 + tid; e < e1; e += 256) {
    int p = packed[e];
    int pos = atomicAdd(&fb[p & 255], 1);
    csr[e0 + pos] = p >> 8;
  }
}

// ---------------- weight prep (single kernel) ----------------
__global__ void prep_weights_kernel(const float* __restrict__ W0, const float* __restrict__ W1,
                                    const float* __restrict__ W2, const float* __restrict__ W3,
                                    const float* __restrict__ Wih0, const float* __restrict__ Whh0,
                                    const float* __restrict__ WihR, const float* __restrict__ WhhR,
                                    const float* __restrict__ b0, const float* __restrict__ bR,
                                    float* __restrict__ ginWT, float* __restrict__ WT0,
                                    float* __restrict__ WTR, float* __restrict__ bc0,
                                    float* __restrict__ bcR) {
  int idx = blockIdx.x * 256 + threadIdx.x;  // grid 2568*256 = 657408 exact
  if (idx < 65536) {
    int m = idx >> 14;
    int r = idx & 16383;
    int k = r >> 7, o = r & 127;
    const float* W = (m == 0) ? W0 : (m == 1) ? W1 : (m == 2) ? W2 : W3;
    ginWT[idx] = W[o * 128 + k];
  } else if (idx < 262144) {
    int t = idx - 65536;
    int k = t >> 9, op = t & 511;
    int j = op >> 2, g = op & 3;
    int row = g * 128 + j;
    WT0[t] = (k < 256) ? Wih0[row * 256 + k] : Whh0[row * 128 + (k - 256)];
  } else if (idx < 655360) {
    int t = idx - 262144;
    int l = t >> 17;
    int rem = t & 131071;
    int k = rem >> 9, op = rem & 511;
    int j = op >> 2, g = op & 3;
    int row = g * 128 + j;
    WTR[t] = (k < 128) ? WihR[((size_t)l * 512 + row) * 128 + k]
                       : WhhR[((size_t)l * 512 + row) * 128 + (k - 128)];
  } else {
    int t = idx - 655360;
    if (t < 512) {
      bc0[t] = b0[(t & 3) * 128 + (t >> 2)];
    } else {
      int u = t - 512;
      int l = u >> 9, op = u & 511;
      bcR[u] = bR[l * 512 + (op & 3) * 128 + (op >> 2)];
    }
  }
}

// ---------------- GIN ----------------

// one wave per node; each 32-lane half loads a full 512B row as float4.
template <bool AFF>
__global__ __launch_bounds__(256) void gin_agg_kernel(
    const float* __restrict__ xin, const int* __restrict__ row_start,
    const int* __restrict__ csr,
    const float* __restrict__ stats, const float* __restrict__ gamma,
    const float* __restrict__ beta, float* __restrict__ outp) {
  __shared__ float sc_s[128], sh_s[128];
  if (AFF) {
    int t = threadIdx.x;
    if (t < 128) {
      const float invN = 1.0f / (float)NN;
      float mm = stats[t] * invN;
      float vv = stats[128 + t] * invN - mm * mm;
      float rs = rsqrtf(vv + 1e-5f);
      float sc = gamma[t] * rs;
      sc_s[t] = sc;
      sh_s[t] = beta[t] - mm * sc;
    }
    __syncthreads();
  }
  int node = blockIdx.x * 4 + (threadIdx.x >> 6);  // exact: 12500*4 = 50000
  int lane = threadIdx.x & 63;
  int half = lane >> 5, ln = lane & 31;
  const float4* x4 = (const float4*)xin;
  float4 sc4 = make_float4(0.f, 0.f, 0.f, 0.f), sh4 = sc4;
  if (AFF) {
    sc4 = *(const float4*)&sc_s[4 * ln];
    sh4 = *(const float4*)&sh_s[4 * ln];
  }
  int s0 = row_start[node], s1 = row_start[node + 1];
  float4 self = x4[(size_t)node * 32 + ln];
  if (AFF) self = aff4(self, sc4, sh4);
  float4 c0 = make_float4(0.f, 0.f, 0.f, 0.f), c1 = c0, c2 = c0, c3 = c0;
  int cnt = s1 - s0;
  int mainEnd = s0 + (cnt & ~15);
  for (int j = s0; j < mainEnd; j += 16) {
    int i0 = csr[j + half + 0];
    int i1 = csr[j + half + 2];
    int i2 = csr[j + half + 4];
    int i3 = csr[j + half + 6];
    int i4 = csr[j + half + 8];
    int i5 = csr[j + half + 10];
    int i6 = csr[j + half + 12];
    int i7 = csr[j + half + 14];
    float4 v0 = x4[(size_t)i0 * 32 + ln];
    float4 v1 = x4[(size_t)i1 * 32 + ln];
    float4 v2 = x4[(size_t)i2 * 32 + ln];
    float4 v3 = x4[(size_t)i3 * 32 + ln];
    float4 v4 = x4[(size_t)i4 * 32 + ln];
    float4 v5 = x4[(size_t)i5 * 32 + ln];
    float4 v6 = x4[(size_t)i6 * 32 + ln];
    float4 v7 = x4[(size_t)i7 * 32 + ln];
    if (AFF) {
      v0 = aff4(v0, sc4, sh4); v1 = aff4(v1, sc4, sh4);
      v2 = aff4(v2, sc4, sh4); v3 = aff4(v3, sc4, sh4);
      v4 = aff4(v4, sc4, sh4); v5 = aff4(v5, sc4, sh4);
      v6 = aff4(v6, sc4, sh4); v7 = aff4(v7, sc4, sh4);
    }
    add4(c0, v0); add4(c1, v1); add4(c2, v2); add4(c3, v3);
    add4(c0, v4); add4(c1, v5); add4(c2, v6); add4(c3, v7);
  }
  for (int j = mainEnd + half; j < s1; j += 2) {
    int i = csr[j];
    float4 v = x4[(size_t)i * 32 + ln];
    if (AFF) v = aff4(v, sc4, sh4);
    add4(c0, v);
  }
  float4 t;
  t.x = (c0.x + c1.x) + (c2.x + c3.x);
  t.y = (c0.y + c1.y) + (c2.y + c3.y);
  t.z = (c0.z + c1.z) + (c2.z + c3.z);
  t.w = (c0.w + c1.w) + (c2.w + c3.w);
  t.x += __shfl_xor(t.x, 32);
  t.y += __shfl_xor(t.y, 32);
  t.z += __shfl_xor(t.z, 32);
  t.w += __shfl_xor(t.w, 32);
  t.x += self.x; t.y += self.y; t.z += self.z; t.w += self.w;
  if (half == 0) ((float4*)outp)[(size_t)node * 32 + ln] = t;
}

// C = f(A) @ W^T + b, f = optional fused BN(stats)+relu; per-channel stats atomics.
template <bool BN>
__global__ __launch_bounds__(256) void gemm_gin_kernel(
    const float* __restrict__ A, const float* __restrict__ WT,
    const float* __restrict__ bias,
    const float* __restrict__ stats, const float* __restrict__ gamma,
    const float* __restrict__ beta,
    float* __restrict__ C,
    float* __restrict__ ssum, float* __restrict__ ssq, int M) {
  __shared__ float As[64][132];
  __shared__ float Wt[128][68];
  __shared__ float bsc[128], bsh[128];
  int tid = threadIdx.x;
  if (BN) {
    if (tid < 128) {
      const float invN = 1.0f / (float)NN;
      float mm = stats[tid] * invN;
      float vv = stats[128 + tid] * invN - mm * mm;
      float rs = rsqrtf(vv + 1e-5f);
      float sc = gamma[tid] * rs;
      bsc[tid] = sc;
      bsh[tid] = beta[tid] - mm * sc;
    }
    __syncthreads();
  }
  int tx = tid & 15, ty = tid >> 4;
  int bx = blockIdx.x & 1, by = blockIdx.x >> 1;
  int row0 = by * 64, c0 = bx * 64;
#pragma unroll
  for (int i = 0; i < 8; ++i) {
    int slot = tid + i * 256;
    int r = slot >> 5, k4 = (slot & 31) << 2;
    float4 v = make_float4(0.f, 0.f, 0.f, 0.f);
    if (row0 + r < M) v = *(const float4*)(A + (size_t)(row0 + r) * 128 + k4);
    if (BN) {
      v.x = fmaxf(fmaf(v.x, bsc[k4 + 0], bsh[k4 + 0]), 0.f);
      v.y = fmaxf(fmaf(v.y, bsc[k4 + 1], bsh[k4 + 1]), 0.f);
      v.z = fmaxf(fmaf(v.z, bsc[k4 + 2], bsh[k4 + 2]), 0.f);
      v.w = fmaxf(fmaf(v.w, bsc[k4 + 3], bsh[k4 + 3]), 0.f);
    }
    *(float4*)&As[r][k4] = v;
  }
#pragma unroll
  for (int i = 0; i < 8; ++i) {
    int slot = tid + i * 256;
    int k = slot >> 4, c4 = (slot & 15) << 2;
    *(float4*)&Wt[k][c4] = *(const float4*)(WT + (size_t)k * 128 + c0 + c4);
  }
  __syncthreads();
  float acc[4][4];
#pragma unroll
  for (int i = 0; i < 4; ++i)
#pragma unroll
    for (int j = 0; j < 4; ++j) acc[i][j] = 0.f;
#pragma unroll 4
  for (int kk = 0; kk < 128; kk += 4) {
    float4 w0 = *(const float4*)&Wt[kk + 0][tx << 2];
    float4 w1 = *(const float4*)&Wt[kk + 1][tx << 2];
    float4 w2 = *(const float4*)&Wt[kk + 2][tx << 2];
    float4 w3 = *(const float4*)&Wt[kk + 3][tx << 2];
#pragma unroll
    for (int i = 0; i < 4; ++i) {
      float4 a = *(const float4*)&As[(ty << 2) + i][kk];
      acc[i][0] += a.x * w0.x + a.y * w1.x + a.z * w2.x + a.w * w3.x;
      acc[i][1] += a.x * w0.y + a.y * w1.y + a.z * w2.y + a.w * w3.y;
      acc[i][2] += a.x * w0.z + a.y * w1.z + a.z * w2.z + a.w * w3.z;
      acc[i][3] += a.x * w0.w + a.y * w1.w + a.z * w2.w + a.w * w3.w;
    }
  }
  __syncthreads();
  float b0v = bias[c0 + (tx << 2) + 0];
  float b1v = bias[c0 + (tx << 2) + 1];
  float b2v = bias[c0 + (tx << 2) + 2];
  float b3v = bias[c0 + (tx << 2) + 3];
  float psum[4] = {0.f, 0.f, 0.f, 0.f}, psq[4] = {0.f, 0.f, 0.f, 0.f};
#pragma unroll
  for (int i = 0; i < 4; ++i) {
    int r = row0 + (ty << 2) + i;
    if (r < M) {
      float4 v;
      v.x = acc[i][0] + b0v; v.y = acc[i][1] + b1v;
      v.z = acc[i][2] + b2v; v.w = acc[i][3] + b3v;
      *(float4*)(C + (size_t)r * 128 + c0 + (tx << 2)) = v;
      psum[0] += v.x; psum[1] += v.y; psum[2] += v.z; psum[3] += v.w;
      psq[0] += v.x * v.x; psq[1] += v.y * v.y; psq[2] += v.z * v.z; psq[3] += v.w * v.w;
    }
  }
  float* red = &As[0][0];
#pragma unroll
  for (int j = 0; j < 4; ++j) {
    red[ty * 68 + (tx << 2) + j] = psum[j];
    red[1088 + ty * 68 + (tx << 2) + j] = psq[j];
  }
  __syncthreads();
  if (tid < 64) {
    float s = 0.f, sq = 0.f;
#pragma unroll
    for (int t = 0; t < 16; ++t) { s += red[t * 68 + tid]; sq += red[1088 + t * 68 + tid]; }
    atomicAdd(&ssum[c0 + tid], s);
    atomicAdd(&ssq[c0 + tid], sq);
  }
}

// ---------------- fused Set2Set: one block per graph, NO grid syncs ----------------
// Per-graph independence: LSTM is row-wise, attention/q_star are per-graph.
// Block g: stage segment x rows (BN4-applied) into LDS once; loop 4 steps of
// {4 mat-vec LSTM cells (weights streamed from L2), in-LDS attention}; final linear.
__global__ void __launch_bounds__(256) set2set_kernel(
    const float* __restrict__ x, const int* __restrict__ gptr,
    const float* __restrict__ stats, const float* __restrict__ gamma,
    const float* __restrict__ beta,
    const float* __restrict__ WT0, const float* __restrict__ WTR,
    const float* __restrict__ bc0, const float* __restrict__ bcR,
    float* __restrict__ ebuf,
    const float* __restrict__ linW, const float* __restrict__ linb,
    float* __restrict__ out) {
  __shared__ float xs[SEG_CAP * 128];   // 131072 B
  __shared__ float es_s[SEG_CAP];
  __shared__ float hcs[4][128];
  __shared__ float ccs[4][128];
  __shared__ float qst[256];
  __shared__ float inp_s[384];
  __shared__ float gates[512];
  __shared__ float bsc[128], bsh[128];
  __shared__ float rpart[4][128];
  __shared__ float wred[8];
  __shared__ float sm2[2];

  int g = blockIdx.x, tid = threadIdx.x;
  int lane = tid & 63, w = tid >> 6;

  if (tid < 128) {
    const float invN = 1.0f / (float)NN;
    float mm = stats[tid] * invN;
    float vv = stats[128 + tid] * invN - mm * mm;
    float rs = rsqrtf(vv + 1e-5f);
    float sc = gamma[tid] * rs;
    bsc[tid] = sc;
    bsh[tid] = beta[tid] - mm * sc;
#pragma unroll
    for (int l = 0; l < 4; ++l) { hcs[l][tid] = 0.f; ccs[l][tid] = 0.f; }
  }
  qst[tid] = 0.f;
  __syncthreads();

  int s0 = gptr[g], s1 = gptr[g + 1];
  int seg = s1 - s0;
  int ncache = seg < SEG_CAP ? seg : SEG_CAP;
  const float2* x2 = (const float2*)x;
  float sc0 = bsc[2 * lane], sc1 = bsc[2 * lane + 1];
  float sh0 = bsh[2 * lane], sh1 = bsh[2 * lane + 1];
  // stage segment into LDS once (BN4-transformed)
  for (int n = w; n < ncache; n += 4) {
    float2 v = x2[(size_t)(s0 + n) * 64 + lane];
    xs[n * 128 + 2 * lane] = fmaxf(fmaf(v.x, sc0, sh0), 0.f);
    xs[n * 128 + 2 * lane + 1] = fmaxf(fmaf(v.y, sc1, sh1), 0.f);
  }
  __syncthreads();

  for (int step = 0; step < 4; ++step) {
    // ---- 4 stacked LSTM cells (mat-vec) ----
    for (int cell = 0; cell < 4; ++cell) {
      const float* WT; const float* bias; int K;
      if (cell == 0) {
        WT = WT0; bias = bc0; K = 384;
        // inp = q_star (256) | old h0 (128)
        inp_s[tid] = qst[tid];
        if (tid < 128) inp_s[256 + tid] = hcs[0][tid];
      } else {
        WT = WTR + (size_t)(cell - 1) * 131072;
        bias = bcR + (cell - 1) * 512; K = 256;
        // inp = new h[cell-1] (128) | old h[cell] (128)
        if (tid < 128) inp_s[tid] = hcs[cell - 1][tid];
        else inp_s[tid] = hcs[cell][tid - 128];
      }
      __syncthreads();
      float a0 = 0.f, a1 = 0.f;
      const float* wp = WT + 2 * tid;
      for (int k = 0; k < K; k += 8) {
        float2 w0 = *(const float2*)(wp + (size_t)(k + 0) * 512);
        float2 w1 = *(const float2*)(wp + (size_t)(k + 1) * 512);
        float2 w2 = *(const float2*)(wp + (size_t)(k + 2) * 512);
        float2 w3 = *(const float2*)(wp + (size_t)(k + 3) * 512);
        float2 w4 = *(const float2*)(wp + (size_t)(k + 4) * 512);
        float2 w5 = *(const float2*)(wp + (size_t)(k + 5) * 512);
        float2 w6 = *(const float2*)(wp + (size_t)(k + 6) * 512);
        float2 w7 = *(const float2*)(wp + (size_t)(k + 7) * 512);
        float4 iA = *(const float4*)&inp_s[k];
        float4 iB = *(const float4*)&inp_s[k + 4];
        a0 += iA.x * w0.x + iA.y * w1.x + iA.z * w2.x + iA.w * w3.x;
        a1 += iA.x * w0.y + iA.y * w1.y + iA.z * w2.y + iA.w * w3.y;
        a0 += iB.x * w4.x + iB.y * w5.x + iB.z * w6.x + iB.w * w7.x;
        a1 += iB.x * w4.y + iB.y * w5.y + iB.z * w6.y + iB.w * w7.y;
      }
      gates[2 * tid] = a0 + bias[2 * tid];
      gates[2 * tid + 1] = a1 + bias[2 * tid + 1];
      __syncthreads();
      if (tid < 128) {
        float ii = gates[4 * tid + 0];
        float ff = gates[4 * tid + 1];
        float gg = gates[4 * tid + 2];
        float oo = gates[4 * tid + 3];
        float cp = ccs[cell][tid];
        float si = 1.f / (1.f + expf(-ii));
        float sf = 1.f / (1.f + expf(-ff));
        float so = 1.f / (1.f + expf(-oo));
        float cn = sf * cp + si * tanhf(gg);
        ccs[cell][tid] = cn;
        hcs[cell][tid] = so * tanhf(cn);
      }
      __syncthreads();
    }
    // ---- attention with q = new h[3] ----
    float qx = hcs[3][2 * lane], qy = hcs[3][2 * lane + 1];
    // pass 1: e + max
    float wmax = -3.0e38f;
    for (int n = w; n < seg; n += 4) {
      float vx, vy;
      if (n < ncache) {
        vx = xs[n * 128 + 2 * lane];
        vy = xs[n * 128 + 2 * lane + 1];
      } else {
        float2 v = x2[(size_t)(s0 + n) * 64 + lane];
        vx = fmaxf(fmaf(v.x, sc0, sh0), 0.f);
        vy = fmaxf(fmaf(v.y, sc1, sh1), 0.f);
      }
      float e = vx * qx + vy * qy;
#pragma unroll
      for (int sh = 32; sh; sh >>= 1) e += __shfl_xor(e, sh);
      if (lane == 0) { if (n < ncache) es_s[n] = e; else ebuf[s0 + n] = e; }
      wmax = fmaxf(wmax, e);
    }
    if (lane == 0) wred[w] = wmax;
    __syncthreads();
    if (tid == 0) sm2[0] = fmaxf(fmaxf(wred[0], wred[1]), fmaxf(wred[2], wred[3]));
    __syncthreads();
    float m = sm2[0];
    // pass 2: sum exp
    float loc = 0.f;
    for (int n = tid; n < seg; n += 256) {
      float e = (n < ncache) ? es_s[n] : ebuf[s0 + n];
      loc += expf(e - m);
    }
#pragma unroll
    for (int sh = 32; sh; sh >>= 1) loc += __shfl_xor(loc, sh);
    __syncthreads();
    if (lane == 0) wred[w] = loc;
    __syncthreads();
    if (tid == 0) sm2[1] = wred[0] + wred[1] + wred[2] + wred[3];
    __syncthreads();
    float inv = 1.0f / sm2[1];
    // pass 3: r = sum a*x
    float rx = 0.f, ry = 0.f;
    for (int n = w; n < seg; n += 4) {
      float e = (n < ncache) ? es_s[n] : ebuf[s0 + n];
      float coef = expf(e - m) * inv;
      float vx, vy;
      if (n < ncache) {
        vx = xs[n * 128 + 2 * lane];
        vy = xs[n * 128 + 2 * lane + 1];
      } else {
        float2 v = x2[(size_t)(s0 + n) * 64 + lane];
        vx = fmaxf(fmaf(v.x, sc0, sh0), 0.f);
        vy = fmaxf(fmaf(v.y, sc1, sh1), 0.f);
      }
      rx += coef * vx; ry += coef * vy;
    }
    rpart[w][2 * lane] = rx;
    rpart[w][2 * lane + 1] = ry;
    __syncthreads();
    if (tid < 128) {
      float r = rpart[0][tid] + rpart[1][tid] + rpart[2][tid] + rpart[3][tid];
      qst[tid] = hcs[3][tid];
      qst[128 + tid] = r;
    }
    __syncthreads();
  }
  // ---- final linear ----
  float val = qst[tid];
  float p0 = val * linW[tid];
  float p1 = val * linW[256 + tid];
#pragma unroll
  for (int sh = 32; sh; sh >>= 1) { p0 += __shfl_xor(p0, sh); p1 += __shfl_xor(p1, sh); }
  if (lane == 0) { wred[w] = p0; wred[4 + w] = p1; }
  __syncthreads();
  if (tid == 0) {
    out[2 * g + 0] = wred[0] + wred[1] + wred[2] + wred[3] + linb[0];
    out[2 * g + 1] = wred[4] + wred[5] + wred[6] + wred[7] + linb[1];
  }
}

// ---------------- launch ----------------

extern "C" void kernel_launch(void* const* d_in, const int* in_sizes, int n_in,
                              void* d_out, int out_size, void* d_ws, size_t ws_size,
                              hipStream_t stream) {
  const float* x = (const float*)d_in[0];
  const int* ei = (const int*)d_in[1];
  const int* batch = (const int*)d_in[2];
  const float* gW[4]  = {(const float*)d_in[3],  (const float*)d_in[7],
                         (const float*)d_in[11], (const float*)d_in[15]};
  const float* gb[4]  = {(const float*)d_in[4],  (const float*)d_in[8],
                         (const float*)d_in[12], (const float*)d_in[16]};
  const float* gga[4] = {(const float*)d_in[5],  (const float*)d_in[9],
                         (const float*)d_in[13], (const float*)d_in[17]};
  const float* gbe[4] = {(const float*)d_in[6],  (const float*)d_in[10],
                         (const float*)d_in[14], (const float*)d_in[18]};
  const float* Wih0 = (const float*)d_in[19];
  const float* Whh0 = (const float*)d_in[20];
  const float* b0   = (const float*)d_in[21];
  const float* WihR = (const float*)d_in[22];
  const float* WhhR = (const float*)d_in[23];
  const float* bR   = (const float*)d_in[24];
  const float* linW = (const float*)d_in[25];
  const float* linb = (const float*)d_in[26];
  float* out = (float*)d_out;

  char* base = (char*)d_ws;
  size_t off = 0;
  auto allocf = [&](size_t n) { float* p = (float*)(base + off); off += n * sizeof(float); return p; };
  float* xa    = allocf(6400000);
  float* xb    = allocf(6400000);
  float* ginWT = allocf(65536);
  float* WT0   = allocf(196608);
  float* WTR   = allocf(393216);
  float* bc0   = allocf(512);
  float* bcR   = allocf(1536);
  float* ebuf  = allocf(50000);
  // ---- zero region: stats only (1024 floats = 256 float4) ----
  float* stats = allocf(1024);     // 4 x (sum128|sq128)
  // ---- ints (all fully written before read; no zeroing needed) ----
  int* row_start = (int*)(base + off); off += 50004 * 4;
  int* gptr = (int*)(base + off); off += 260 * 4;
  int* csr = (int*)(base + off); off += 800000 * 4;
  int* packed = (int*)(base + off); off += 800000 * 4;
  int* partial = (int*)(base + off); off += NBIN * NBLK * 4;
  int* block_base = (int*)(base + off); off += NBIN * NBLK * 4;
  int* total = (int*)(base + off); off += 256 * 4;
  int* coarse_base = (int*)(base + off); off += 260 * 4;
  (void)ws_size; (void)in_sizes; (void)n_in; (void)out_size;

  // prep
  zero4_kernel<<<1, 256, 0, stream>>>((float4*)stats, 256);
  gptr_boundary_kernel<<<196, 256, 0, stream>>>(batch, gptr);
  coarse_hist_kernel<<<NBLK, 256, 0, stream>>>(ei, partial);
  scan_partials_kernel<<<NBIN, 256, 0, stream>>>(partial, block_base, total);
  scan_totals_kernel<<<1, 256, 0, stream>>>(total, coarse_base);
  bucket_scatter_kernel<<<NBLK, 256, 0, stream>>>(ei, coarse_base, block_base, packed);
  csr_finalize_kernel<<<NBIN, 256, 0, stream>>>(packed, coarse_base, row_start, csr);
  prep_weights_kernel<<<2568, 256, 0, stream>>>(gW[0], gW[1], gW[2], gW[3], Wih0, Whh0,
                                                WihR, WhhR, b0, bR, ginWT, WT0, WTR, bc0, bcR);

  // GIN layer 1
  gin_agg_kernel<false><<<12500, 256, 0, stream>>>(x, row_start, csr,
                                                   nullptr, nullptr, nullptr, xb);
  gemm_gin_kernel<false><<<1564, 256, 0, stream>>>(xb, ginWT + 0 * 16384, gb[0],
                                                   nullptr, nullptr, nullptr,
                                                   xa, stats + 0, stats + 128, NN);
  gemm_gin_kernel<true><<<1564, 256, 0, stream>>>(xa, ginWT + 1 * 16384, gb[1],
                                                  stats + 0, gga[0], gbe[0],
                                                  xb, stats + 256, stats + 384, NN);
  // GIN layer 2 (BN2 finalize+affine+relu fused into the gather)
  gin_agg_kernel<true><<<12500, 256, 0, stream>>>(xb, row_start, csr,
                                                  stats + 256, gga[1], gbe[1], xa);
  gemm_gin_kernel<false><<<1564, 256, 0, stream>>>(xa, ginWT + 2 * 16384, gb[2],
                                                   nullptr, nullptr, nullptr,
                                                   xb, stats + 512, stats + 640, NN);
  gemm_gin_kernel<true><<<1564, 256, 0, stream>>>(xb, ginWT + 3 * 16384, gb[3],
                                                  stats + 512, gga[2], gbe[2],
                                                  xa, stats + 768, stats + 896, NN);
  // xa holds pre-BN4 features; BN4 fused into set2set x staging

  // fused Set2Set: one block per graph, no grid-wide syncs
  set2set_kernel<<<256, 256, 0, stream>>>(xa, gptr, stats + 768, gga[3], gbe[3],
                                          WT0, WTR, bc0, bcR, ebuf, linW, linb, out);
}

// Round 7
// 650.657 us; speedup vs baseline: 2.0043x; 1.1015x over previous
//
#include <hip/hip_runtime.h>
#include <math.h>

#define NN 50000
#define EE 800000
#define BBG 256
#define HHC 128
#define ESC 512     // per-graph e-cache entries in LDS
#define NBIN 196    // coarse bins of 256 nodes
#define NBLK 196    // blocks in K1/K3 (4096 edges each)

__device__ __forceinline__ float4 aff4(float4 v, float4 sc, float4 sh) {
  v.x = fmaxf(fmaf(v.x, sc.x, sh.x), 0.f);
  v.y = fmaxf(fmaf(v.y, sc.y, sh.y), 0.f);
  v.z = fmaxf(fmaf(v.z, sc.z, sh.z), 0.f);
  v.w = fmaxf(fmaf(v.w, sc.w, sh.w), 0.f);
  return v;
}
__device__ __forceinline__ void add4(float4& a, float4 b) {
  a.x += b.x; a.y += b.y; a.z += b.z; a.w += b.w;
}

// ---------------- utility ----------------

__global__ void zero4_kernel(float4* p, int n) {
  int i = blockIdx.x * 256 + threadIdx.x;
  if (i < n) p[i] = make_float4(0.f, 0.f, 0.f, 0.f);
}

// batch is sorted: gptr[g] = first index with batch >= g; gptr[256] = NN
__global__ void gptr_boundary_kernel(const int* __restrict__ batch, int* __restrict__ gptr) {
  int i = blockIdx.x * 256 + threadIdx.x;
  if (i >= NN) return;
  int b = batch[i];
  int prev = (i == 0) ? -1 : batch[i - 1];
  for (int g = prev + 1; g <= b; ++g) gptr[g] = i;
  if (i == NN - 1) {
    for (int g = b + 1; g <= BBG; ++g) gptr[g] = NN;
  }
}

// ---- atomic-free CSR build (two-level counting sort) ----

__global__ __launch_bounds__(256) void coarse_hist_kernel(const int* __restrict__ ei,
                                                          int* __restrict__ partial) {
  __shared__ int hist[NBIN];
  int tid = threadIdx.x, b = blockIdx.x;
  if (tid < NBIN) hist[tid] = 0;
  __syncthreads();
  const int4* dst4 = (const int4*)(ei + EE);
#pragma unroll
  for (int c = 0; c < 4; ++c) {
    int idx = b * 1024 + c * 256 + tid;
    if (idx < EE / 4) {
      int4 d = dst4[idx];
      atomicAdd(&hist[d.x >> 8], 1);
      atomicAdd(&hist[d.y >> 8], 1);
      atomicAdd(&hist[d.z >> 8], 1);
      atomicAdd(&hist[d.w >> 8], 1);
    }
  }
  __syncthreads();
  if (tid < NBIN) partial[tid * NBLK + b] = hist[tid];
}

__global__ void scan_partials_kernel(const int* __restrict__ partial,
                                     int* __restrict__ block_base, int* __restrict__ total) {
  __shared__ int buf[256];
  int bin = blockIdx.x, tid = threadIdx.x;
  int v = (tid < NBLK) ? partial[bin * NBLK + tid] : 0;
  buf[tid] = v;
  __syncthreads();
  for (int off = 1; off < 256; off <<= 1) {
    int t = (tid >= off) ? buf[tid - off] : 0;
    __syncthreads();
    buf[tid] += t;
    __syncthreads();
  }
  if (tid < NBLK) block_base[bin * NBLK + tid] = buf[tid] - v;
  if (tid == 255) total[bin] = buf[255];
}

__global__ void scan_totals_kernel(const int* __restrict__ total, int* __restrict__ coarse_base) {
  __shared__ int buf[256];
  int tid = threadIdx.x;
  int v = (tid < NBIN) ? total[tid] : 0;
  buf[tid] = v;
  __syncthreads();
  for (int off = 1; off < 256; off <<= 1) {
    int t = (tid >= off) ? buf[tid - off] : 0;
    __syncthreads();
    buf[tid] += t;
    __syncthreads();
  }
  if (tid < NBIN) coarse_base[tid] = buf[tid] - v;
  if (tid == 255) coarse_base[NBIN] = buf[255];
}

__global__ __launch_bounds__(256) void bucket_scatter_kernel(const int* __restrict__ ei,
                                                             const int* __restrict__ coarse_base,
                                                             const int* __restrict__ block_base,
                                                             int* __restrict__ packed) {
  __shared__ int cursor[NBIN];
  int tid = threadIdx.x, b = blockIdx.x;
  if (tid < NBIN) cursor[tid] = coarse_base[tid] + block_base[tid * NBLK + b];
  __syncthreads();
  const int4* src4 = (const int4*)ei;
  const int4* dst4 = (const int4*)(ei + EE);
#pragma unroll
  for (int c = 0; c < 4; ++c) {
    int idx = b * 1024 + c * 256 + tid;
    if (idx < EE / 4) {
      int4 s = src4[idx];
      int4 d = dst4[idx];
      int p;
      p = atomicAdd(&cursor[d.x >> 8], 1); packed[p] = (s.x << 8) | (d.x & 255);
      p = atomicAdd(&cursor[d.y >> 8], 1); packed[p] = (s.y << 8) | (d.y & 255);
      p = atomicAdd(&cursor[d.z >> 8], 1); packed[p] = (s.z << 8) | (d.z & 255);
      p = atomicAdd(&cursor[d.w >> 8], 1); packed[p] = (s.w << 8) | (d.w & 255);
    }
  }
}

__global__ __launch_bounds__(256) void csr_finalize_kernel(const int* __restrict__ packed,
                                                           const int* __restrict__ coarse_base,
                                                           int* __restrict__ row_start,
                                                           int* __restrict__ csr) {
  __shared__ int fh[256];
  __shared__ int fb[256];
  int bin = blockIdx.x, tid = threadIdx.x;
  int e0 = coarse_base[bin], e1 = coarse_base[bin + 1];
  fh[tid] = 0;
  __syncthreads();
  for (int e = e0 + tid; e < e1; e += 256) atomicAdd(&fh[packed[e] & 255], 1);
  __syncthreads();
  int v = fh[tid];
  fb[tid] = v;
  __syncthreads();
  for (int off = 1; off < 256; off <<= 1) {
    int t = (tid >= off) ? fb[tid - off] : 0;
    __syncthreads();
    fb[tid] += t;
    __syncthreads();
  }
  int excl = fb[tid] - v;
  int node = bin * 256 + tid;
  if (node < NN) row_start[node] = e0 + excl;
  if (bin == NBIN - 1 && tid == 0) row_start[NN] = EE;
  __syncthreads();
  fb[tid] = excl;  // cursor
  __syncthreads();
  for (int e = e0 + tid; e < e1; e += 256) {
    int p = packed[e];
    int pos = atomicAdd(&fb[p & 255], 1);
    csr[e0 + pos] = p >> 8;
  }
}

// ---------------- weight prep (single kernel) ----------------
__global__ void prep_weights_kernel(const float* __restrict__ W0, const float* __restrict__ W1,
                                    const float* __restrict__ W2, const float* __restrict__ W3,
                                    const float* __restrict__ Wih0, const float* __restrict__ Whh0,
                                    const float* __restrict__ WihR, const float* __restrict__ WhhR,
                                    const float* __restrict__ b0, const float* __restrict__ bR,
                                    float* __restrict__ ginWT, float* __restrict__ WT0,
                                    float* __restrict__ WTR, float* __restrict__ bc0,
                                    float* __restrict__ bcR) {
  int idx = blockIdx.x * 256 + threadIdx.x;  // grid 2568*256 = 657408 exact
  if (idx < 65536) {
    int m = idx >> 14;
    int r = idx & 16383;
    int k = r >> 7, o = r & 127;
    const float* W = (m == 0) ? W0 : (m == 1) ? W1 : (m == 2) ? W2 : W3;
    ginWT[idx] = W[o * 128 + k];
  } else if (idx < 262144) {
    int t = idx - 65536;
    int k = t >> 9, op = t & 511;
    int j = op >> 2, g = op & 3;
    int row = g * 128 + j;
    WT0[t] = (k < 256) ? Wih0[row * 256 + k] : Whh0[row * 128 + (k - 256)];
  } else if (idx < 655360) {
    int t = idx - 262144;
    int l = t >> 17;
    int rem = t & 131071;
    int k = rem >> 9, op = rem & 511;
    int j = op >> 2, g = op & 3;
    int row = g * 128 + j;
    WTR[t] = (k < 128) ? WihR[((size_t)l * 512 + row) * 128 + k]
                       : WhhR[((size_t)l * 512 + row) * 128 + (k - 128)];
  } else {
    int t = idx - 655360;
    if (t < 512) {
      bc0[t] = b0[(t & 3) * 128 + (t >> 2)];
    } else {
      int u = t - 512;
      int l = u >> 9, op = u & 511;
      bcR[u] = bR[l * 512 + (op & 3) * 128 + (op >> 2)];
    }
  }
}

// ---------------- GIN ----------------

// one wave per node; each 32-lane half loads a full 512B row as float4.
template <bool AFF>
__global__ __launch_bounds__(256) void gin_agg_kernel(
    const float* __restrict__ xin, const int* __restrict__ row_start,
    const int* __restrict__ csr,
    const float* __restrict__ stats, const float* __restrict__ gamma,
    const float* __restrict__ beta, float* __restrict__ outp) {
  __shared__ float sc_s[128], sh_s[128];
  if (AFF) {
    int t = threadIdx.x;
    if (t < 128) {
      const float invN = 1.0f / (float)NN;
      float mm = stats[t] * invN;
      float vv = stats[128 + t] * invN - mm * mm;
      float rs = rsqrtf(vv + 1e-5f);
      float sc = gamma[t] * rs;
      sc_s[t] = sc;
      sh_s[t] = beta[t] - mm * sc;
    }
    __syncthreads();
  }
  int node = blockIdx.x * 4 + (threadIdx.x >> 6);  // exact: 12500*4 = 50000
  int lane = threadIdx.x & 63;
  int half = lane >> 5, ln = lane & 31;
  const float4* x4 = (const float4*)xin;
  float4 sc4 = make_float4(0.f, 0.f, 0.f, 0.f), sh4 = sc4;
  if (AFF) {
    sc4 = *(const float4*)&sc_s[4 * ln];
    sh4 = *(const float4*)&sh_s[4 * ln];
  }
  int s0 = row_start[node], s1 = row_start[node + 1];
  float4 self = x4[(size_t)node * 32 + ln];
  if (AFF) self = aff4(self, sc4, sh4);
  float4 c0 = make_float4(0.f, 0.f, 0.f, 0.f), c1 = c0, c2 = c0, c3 = c0;
  int cnt = s1 - s0;
  int mainEnd = s0 + (cnt & ~15);
  for (int j = s0; j < mainEnd; j += 16) {
    int i0 = csr[j + half + 0];
    int i1 = csr[j + half + 2];
    int i2 = csr[j + half + 4];
    int i3 = csr[j + half + 6];
    int i4 = csr[j + half + 8];
    int i5 = csr[j + half + 10];
    int i6 = csr[j + half + 12];
    int i7 = csr[j + half + 14];
    float4 v0 = x4[(size_t)i0 * 32 + ln];
    float4 v1 = x4[(size_t)i1 * 32 + ln];
    float4 v2 = x4[(size_t)i2 * 32 + ln];
    float4 v3 = x4[(size_t)i3 * 32 + ln];
    float4 v4 = x4[(size_t)i4 * 32 + ln];
    float4 v5 = x4[(size_t)i5 * 32 + ln];
    float4 v6 = x4[(size_t)i6 * 32 + ln];
    float4 v7 = x4[(size_t)i7 * 32 + ln];
    if (AFF) {
      v0 = aff4(v0, sc4, sh4); v1 = aff4(v1, sc4, sh4);
      v2 = aff4(v2, sc4, sh4); v3 = aff4(v3, sc4, sh4);
      v4 = aff4(v4, sc4, sh4); v5 = aff4(v5, sc4, sh4);
      v6 = aff4(v6, sc4, sh4); v7 = aff4(v7, sc4, sh4);
    }
    add4(c0, v0); add4(c1, v1); add4(c2, v2); add4(c3, v3);
    add4(c0, v4); add4(c1, v5); add4(c2, v6); add4(c3, v7);
  }
  for (int j = mainEnd + half; j < s1; j += 2) {
    int i = csr[j];
    float4 v = x4[(size_t)i * 32 + ln];
    if (AFF) v = aff4(v, sc4, sh4);
    add4(c0, v);
  }
  float4 t;
  t.x = (c0.x + c1.x) + (c2.x + c3.x);
  t.y = (c0.y + c1.y) + (c2.y + c3.y);
  t.z = (c0.z + c1.z) + (c2.z + c3.z);
  t.w = (c0.w + c1.w) + (c2.w + c3.w);
  t.x += __shfl_xor(t.x, 32);
  t.y += __shfl_xor(t.y, 32);
  t.z += __shfl_xor(t.z, 32);
  t.w += __shfl_xor(t.w, 32);
  t.x += self.x; t.y += self.y; t.z += self.z; t.w += self.w;
  if (half == 0) ((float4*)outp)[(size_t)node * 32 + ln] = t;
}

// C = f(A) @ W^T + b, f = optional fused BN(stats)+relu; per-channel stats atomics.
template <bool BN>
__global__ __launch_bounds__(256) void gemm_gin_kernel(
    const float* __restrict__ A, const float* __restrict__ WT,
    const float* __restrict__ bias,
    const float* __restrict__ stats, const float* __restrict__ gamma,
    const float* __restrict__ beta,
    float* __restrict__ C,
    float* __restrict__ ssum, float* __restrict__ ssq, int M) {
  __shared__ float As[64][132];
  __shared__ float Wt[128][68];
  __shared__ float bsc[128], bsh[128];
  int tid = threadIdx.x;
  if (BN) {
    if (tid < 128) {
      const float invN = 1.0f / (float)NN;
      float mm = stats[tid] * invN;
      float vv = stats[128 + tid] * invN - mm * mm;
      float rs = rsqrtf(vv + 1e-5f);
      float sc = gamma[tid] * rs;
      bsc[tid] = sc;
      bsh[tid] = beta[tid] - mm * sc;
    }
    __syncthreads();
  }
  int tx = tid & 15, ty = tid >> 4;
  int bx = blockIdx.x & 1, by = blockIdx.x >> 1;
  int row0 = by * 64, c0 = bx * 64;
#pragma unroll
  for (int i = 0; i < 8; ++i) {
    int slot = tid + i * 256;
    int r = slot >> 5, k4 = (slot & 31) << 2;
    float4 v = make_float4(0.f, 0.f, 0.f, 0.f);
    if (row0 + r < M) v = *(const float4*)(A + (size_t)(row0 + r) * 128 + k4);
    if (BN) {
      v.x = fmaxf(fmaf(v.x, bsc[k4 + 0], bsh[k4 + 0]), 0.f);
      v.y = fmaxf(fmaf(v.y, bsc[k4 + 1], bsh[k4 + 1]), 0.f);
      v.z = fmaxf(fmaf(v.z, bsc[k4 + 2], bsh[k4 + 2]), 0.f);
      v.w = fmaxf(fmaf(v.w, bsc[k4 + 3], bsh[k4 + 3]), 0.f);
    }
    *(float4*)&As[r][k4] = v;
  }
#pragma unroll
  for (int i = 0; i < 8; ++i) {
    int slot = tid + i * 256;
    int k = slot >> 4, c4 = (slot & 15) << 2;
    *(float4*)&Wt[k][c4] = *(const float4*)(WT + (size_t)k * 128 + c0 + c4);
  }
  __syncthreads();
  float acc[4][4];
#pragma unroll
  for (int i = 0; i < 4; ++i)
#pragma unroll
    for (int j = 0; j < 4; ++j) acc[i][j] = 0.f;
#pragma unroll 4
  for (int kk = 0; kk < 128; kk += 4) {
    float4 w0 = *(const float4*)&Wt[kk + 0][tx << 2];
    float4 w1 = *(const float4*)&Wt[kk + 1][tx << 2];
    float4 w2 = *(const float4*)&Wt[kk + 2][tx << 2];
    float4 w3 = *(const float4*)&Wt[kk + 3][tx << 2];
#pragma unroll
    for (int i = 0; i < 4; ++i) {
      float4 a = *(const float4*)&As[(ty << 2) + i][kk];
      acc[i][0] += a.x * w0.x + a.y * w1.x + a.z * w2.x + a.w * w3.x;
      acc[i][1] += a.x * w0.y + a.y * w1.y + a.z * w2.y + a.w * w3.y;
      acc[i][2] += a.x * w0.z + a.y * w1.z + a.z * w2.z + a.w * w3.z;
      acc[i][3] += a.x * w0.w + a.y * w1.w + a.z * w2.w + a.w * w3.w;
    }
  }
  __syncthreads();
  float b0v = bias[c0 + (tx << 2) + 0];
  float b1v = bias[c0 + (tx << 2) + 1];
  float b2v = bias[c0 + (tx << 2) + 2];
  float b3v = bias[c0 + (tx << 2) + 3];
  float psum[4] = {0.f, 0.f, 0.f, 0.f}, psq[4] = {0.f, 0.f, 0.f, 0.f};
#pragma unroll
  for (int i = 0; i < 4; ++i) {
    int r = row0 + (ty << 2) + i;
    if (r < M) {
      float4 v;
      v.x = acc[i][0] + b0v; v.y = acc[i][1] + b1v;
      v.z = acc[i][2] + b2v; v.w = acc[i][3] + b3v;
      *(float4*)(C + (size_t)r * 128 + c0 + (tx << 2)) = v;
      psum[0] += v.x; psum[1] += v.y; psum[2] += v.z; psum[3] += v.w;
      psq[0] += v.x * v.x; psq[1] += v.y * v.y; psq[2] += v.z * v.z; psq[3] += v.w * v.w;
    }
  }
  float* red = &As[0][0];
#pragma unroll
  for (int j = 0; j < 4; ++j) {
    red[ty * 68 + (tx << 2) + j] = psum[j];
    red[1088 + ty * 68 + (tx << 2) + j] = psq[j];
  }
  __syncthreads();
  if (tid < 64) {
    float s = 0.f, sq = 0.f;
#pragma unroll
    for (int t = 0; t < 16; ++t) { s += red[t * 68 + tid]; sq += red[1088 + t * 68 + tid]; }
    atomicAdd(&ssum[c0 + tid], s);
    atomicAdd(&ssq[c0 + tid], sq);
  }
}

// ---------------- fused Set2Set v2: 2 graphs/block, 1024 threads, no grid sync --------
// LSTM mat-vec: 8 K-slices x 128 col-groups; each thread float4-loads weights
// (coalesced, 8-deep unroll = 128B/thread in flight) and accumulates BOTH graphs.
// Attention: two 8-wave halves, one graph each; x read from L2/L3 (no LDS x cache).
__global__ void __launch_bounds__(1024) set2set_kernel(
    const float* __restrict__ x, const int* __restrict__ gptr,
    const float* __restrict__ stats, const float* __restrict__ gamma,
    const float* __restrict__ beta,
    const float* __restrict__ WT0, const float* __restrict__ WTR,
    const float* __restrict__ bc0, const float* __restrict__ bcR,
    float* __restrict__ ebuf,
    const float* __restrict__ linW, const float* __restrict__ linb,
    float* __restrict__ out) {
  __shared__ float wpart[2][8][512];   // 32 KB
  __shared__ float inp_s[2][384];
  __shared__ float hcs[2][4][128];
  __shared__ float ccs[2][4][128];
  __shared__ float qst[2][256];
  __shared__ float es[2][ESC];         // 4 KB
  __shared__ float bsc[128], bsh[128];
  __shared__ float rpart[2][8][128];   // 8 KB
  __shared__ float wred[2][8];
  __shared__ float smax[2], ssum[2];
  __shared__ float fred[2][2][4];

  int blk = blockIdx.x, tid = threadIdx.x;
  int half = tid >> 9, htid = tid & 511;
  int w8 = htid >> 6, lane = htid & 63;
  int g = 2 * blk + half;

  // init
  if (tid < 128) {
    const float invN = 1.0f / (float)NN;
    float mm = stats[tid] * invN;
    float vv = stats[128 + tid] * invN - mm * mm;
    float rs = rsqrtf(vv + 1e-5f);
    float sc = gamma[tid] * rs;
    bsc[tid] = sc;
    bsh[tid] = beta[tid] - mm * sc;
  }
  if (tid < 512) ((float*)qst)[tid] = 0.f;
  ((float*)hcs)[tid] = 0.f;
  ((float*)ccs)[tid] = 0.f;
  __syncthreads();

  int s0 = gptr[g], s1 = gptr[g + 1];
  int seg = s1 - s0;
  const float2* x2 = (const float2*)x;
  float sc0 = bsc[2 * lane], sc1 = bsc[2 * lane + 1];
  float sh0 = bsh[2 * lane], sh1 = bsh[2 * lane + 1];

  int s_ = tid >> 7, cg = tid & 127;   // matvec role: K-slice, col-group

  for (int step = 0; step < 4; ++step) {
    // ---- 4 stacked LSTM cells ----
    for (int cell = 0; cell < 4; ++cell) {
      const float* WT; const float* bias; int K;
      if (cell == 0) {
        WT = WT0; bias = bc0; K = 384;
        if (tid < 256) inp_s[0][tid] = qst[0][tid];
        else if (tid < 512) inp_s[1][tid - 256] = qst[1][tid - 256];
        else if (tid < 640) inp_s[0][256 + tid - 512] = hcs[0][0][tid - 512];
        else if (tid < 768) inp_s[1][256 + tid - 640] = hcs[1][0][tid - 640];
      } else {
        WT = WTR + (size_t)(cell - 1) * 131072;
        bias = bcR + (cell - 1) * 512; K = 256;
        if (tid < 128) inp_s[0][tid] = hcs[0][cell - 1][tid];
        else if (tid < 256) inp_s[1][tid - 128] = hcs[1][cell - 1][tid - 128];
        else if (tid < 384) inp_s[0][128 + tid - 256] = hcs[0][cell][tid - 256];
        else if (tid < 512) inp_s[1][128 + tid - 384] = hcs[1][cell][tid - 384];
      }
      __syncthreads();
      int kper = K >> 3;
      int k0 = s_ * kper;
      const float* wp = WT + 4 * cg;
      float4 a0 = make_float4(0.f, 0.f, 0.f, 0.f), a1 = a0;
      for (int k = k0; k < k0 + kper; k += 8) {
        float4 w0 = *(const float4*)(wp + (size_t)(k + 0) * 512);
        float4 w1 = *(const float4*)(wp + (size_t)(k + 1) * 512);
        float4 w2 = *(const float4*)(wp + (size_t)(k + 2) * 512);
        float4 w3 = *(const float4*)(wp + (size_t)(k + 3) * 512);
        float4 w4 = *(const float4*)(wp + (size_t)(k + 4) * 512);
        float4 w5 = *(const float4*)(wp + (size_t)(k + 5) * 512);
        float4 w6 = *(const float4*)(wp + (size_t)(k + 6) * 512);
        float4 w7 = *(const float4*)(wp + (size_t)(k + 7) * 512);
#pragma unroll
        for (int t = 0; t < 8; ++t) {
          float i0 = inp_s[0][k + t];
          float i1 = inp_s[1][k + t];
          const float4* wv = (t == 0) ? &w0 : (t == 1) ? &w1 : (t == 2) ? &w2 :
                             (t == 3) ? &w3 : (t == 4) ? &w4 : (t == 5) ? &w5 :
                             (t == 6) ? &w6 : &w7;
          a0.x += i0 * wv->x; a0.y += i0 * wv->y; a0.z += i0 * wv->z; a0.w += i0 * wv->w;
          a1.x += i1 * wv->x; a1.y += i1 * wv->y; a1.z += i1 * wv->z; a1.w += i1 * wv->w;
        }
      }
      *(float4*)&wpart[0][s_][4 * cg] = a0;
      *(float4*)&wpart[1][s_][4 * cg] = a1;
      __syncthreads();
      if (tid < 256) {
        int gg = tid >> 7, j = tid & 127;
        float gi = bias[4 * j + 0], gf = bias[4 * j + 1];
        float gc = bias[4 * j + 2], go = bias[4 * j + 3];
#pragma unroll
        for (int s = 0; s < 8; ++s) {
          gi += wpart[gg][s][4 * j + 0];
          gf += wpart[gg][s][4 * j + 1];
          gc += wpart[gg][s][4 * j + 2];
          go += wpart[gg][s][4 * j + 3];
        }
        float cp = ccs[gg][cell][j];
        float si = 1.f / (1.f + expf(-gi));
        float sf = 1.f / (1.f + expf(-gf));
        float so = 1.f / (1.f + expf(-go));
        float cn = sf * cp + si * tanhf(gc);
        ccs[gg][cell][j] = cn;
        hcs[gg][cell][j] = so * tanhf(cn);
      }
      __syncthreads();
    }
    // ---- attention: half-block per graph, q = new h[3] ----
    float qx = hcs[half][3][2 * lane], qy = hcs[half][3][2 * lane + 1];
    // pass 1: e + max
    float wmax = -3.0e38f;
    for (int n = w8; n < seg; n += 8) {
      float2 v = x2[(size_t)(s0 + n) * 64 + lane];
      float vx = fmaxf(fmaf(v.x, sc0, sh0), 0.f);
      float vy = fmaxf(fmaf(v.y, sc1, sh1), 0.f);
      float e = vx * qx + vy * qy;
#pragma unroll
      for (int sh = 32; sh; sh >>= 1) e += __shfl_xor(e, sh);
      if (lane == 0) { if (n < ESC) es[half][n] = e; else ebuf[s0 + n] = e; }
      wmax = fmaxf(wmax, e);
    }
    if (lane == 0) wred[half][w8] = wmax;
    __syncthreads();
    if (htid == 0) {
      float m = wred[half][0];
#pragma unroll
      for (int t = 1; t < 8; ++t) m = fmaxf(m, wred[half][t]);
      smax[half] = m;
    }
    __syncthreads();
    float m = smax[half];
    // pass 2: sum exp
    float loc = 0.f;
    for (int n = htid; n < seg; n += 512) {
      float e = (n < ESC) ? es[half][n] : ebuf[s0 + n];
      loc += expf(e - m);
    }
#pragma unroll
    for (int sh = 32; sh; sh >>= 1) loc += __shfl_xor(loc, sh);
    __syncthreads();
    if (lane == 0) wred[half][w8] = loc;
    __syncthreads();
    if (htid == 0) {
      float s = 0.f;
#pragma unroll
      for (int t = 0; t < 8; ++t) s += wred[half][t];
      ssum[half] = s;
    }
    __syncthreads();
    float inv = 1.0f / ssum[half];
    // pass 3: r = sum a*x
    float rx = 0.f, ry = 0.f;
    for (int n = w8; n < seg; n += 8) {
      float e = (n < ESC) ? es[half][n] : ebuf[s0 + n];
      float coef = expf(e - m) * inv;
      float2 v = x2[(size_t)(s0 + n) * 64 + lane];
      float vx = fmaxf(fmaf(v.x, sc0, sh0), 0.f);
      float vy = fmaxf(fmaf(v.y, sc1, sh1), 0.f);
      rx += coef * vx; ry += coef * vy;
    }
    rpart[half][w8][2 * lane] = rx;
    rpart[half][w8][2 * lane + 1] = ry;
    __syncthreads();
    if (htid < 128) {
      float r = 0.f;
#pragma unroll
      for (int t = 0; t < 8; ++t) r += rpart[half][t][htid];
      qst[half][htid] = hcs[half][3][htid];
      qst[half][128 + htid] = r;
    }
    __syncthreads();
  }
  // ---- final linear ----
  if (htid < 256) {
    float val = qst[half][htid];
    float p0 = val * linW[htid];
    float p1 = val * linW[256 + htid];
#pragma unroll
    for (int sh = 32; sh; sh >>= 1) { p0 += __shfl_xor(p0, sh); p1 += __shfl_xor(p1, sh); }
    if (lane == 0) { fred[half][0][w8] = p0; fred[half][1][w8] = p1; }
  }
  __syncthreads();
  if (htid == 0) {
    out[2 * g + 0] = fred[half][0][0] + fred[half][0][1] + fred[half][0][2] +
                     fred[half][0][3] + linb[0];
    out[2 * g + 1] = fred[half][1][0] + fred[half][1][1] + fred[half][1][2] +
                     fred[half][1][3] + linb[1];
  }
}

// ---------------- launch ----------------

extern "C" void kernel_launch(void* const* d_in, const int* in_sizes, int n_in,
                              void* d_out, int out_size, void* d_ws, size_t ws_size,
                              hipStream_t stream) {
  const float* x = (const float*)d_in[0];
  const int* ei = (const int*)d_in[1];
  const int* batch = (const int*)d_in[2];
  const float* gW[4]  = {(const float*)d_in[3],  (const float*)d_in[7],
                         (const float*)d_in[11], (const float*)d_in[15]};
  const float* gb[4]  = {(const float*)d_in[4],  (const float*)d_in[8],
                         (const float*)d_in[12], (const float*)d_in[16]};
  const float* gga[4] = {(const float*)d_in[5],  (const float*)d_in[9],
                         (const float*)d_in[13], (const float*)d_in[17]};
  const float* gbe[4] = {(const float*)d_in[6],  (const float*)d_in[10],
                         (const float*)d_in[14], (const float*)d_in[18]};
  const float* Wih0 = (const float*)d_in[19];
  const float* Whh0 = (const float*)d_in[20];
  const float* b0   = (const float*)d_in[21];
  const float* WihR = (const float*)d_in[22];
  const float* WhhR = (const float*)d_in[23];
  const float* bR   = (const float*)d_in[24];
  const float* linW = (const float*)d_in[25];
  const float* linb = (const float*)d_in[26];
  float* out = (float*)d_out;

  char* base = (char*)d_ws;
  size_t off = 0;
  auto allocf = [&](size_t n) { float* p = (float*)(base + off); off += n * sizeof(float); return p; };
  float* xa    = allocf(6400000);
  float* xb    = allocf(6400000);
  float* ginWT = allocf(65536);
  float* WT0   = allocf(196608);
  float* WTR   = allocf(393216);
  float* bc0   = allocf(512);
  float* bcR   = allocf(1536);
  float* ebuf  = allocf(50000);
  // ---- zero region: stats only (1024 floats = 256 float4) ----
  float* stats = allocf(1024);     // 4 x (sum128|sq128)
  // ---- ints (all fully written before read; no zeroing needed) ----
  int* row_start = (int*)(base + off); off += 50004 * 4;
  int* gptr = (int*)(base + off); off += 260 * 4;
  int* csr = (int*)(base + off); off += 800000 * 4;
  int* packed = (int*)(base + off); off += 800000 * 4;
  int* partial = (int*)(base + off); off += NBIN * NBLK * 4;
  int* block_base = (int*)(base + off); off += NBIN * NBLK * 4;
  int* total = (int*)(base + off); off += 256 * 4;
  int* coarse_base = (int*)(base + off); off += 260 * 4;
  (void)ws_size; (void)in_sizes; (void)n_in; (void)out_size;

  // prep
  zero4_kernel<<<1, 256, 0, stream>>>((float4*)stats, 256);
  gptr_boundary_kernel<<<196, 256, 0, stream>>>(batch, gptr);
  coarse_hist_kernel<<<NBLK, 256, 0, stream>>>(ei, partial);
  scan_partials_kernel<<<NBIN, 256, 0, stream>>>(partial, block_base, total);
  scan_totals_kernel<<<1, 256, 0, stream>>>(total, coarse_base);
  bucket_scatter_kernel<<<NBLK, 256, 0, stream>>>(ei, coarse_base, block_base, packed);
  csr_finalize_kernel<<<NBIN, 256, 0, stream>>>(packed, coarse_base, row_start, csr);
  prep_weights_kernel<<<2568, 256, 0, stream>>>(gW[0], gW[1], gW[2], gW[3], Wih0, Whh0,
                                                WihR, WhhR, b0, bR, ginWT, WT0, WTR, bc0, bcR);

  // GIN layer 1
  gin_agg_kernel<false><<<12500, 256, 0, stream>>>(x, row_start, csr,
                                                   nullptr, nullptr, nullptr, xb);
  gemm_gin_kernel<false><<<1564, 256, 0, stream>>>(xb, ginWT + 0 * 16384, gb[0],
                                                   nullptr, nullptr, nullptr,
                                                   xa, stats + 0, stats + 128, NN);
  gemm_gin_kernel<true><<<1564, 256, 0, stream>>>(xa, ginWT + 1 * 16384, gb[1],
                                                  stats + 0, gga[0], gbe[0],
                                                  xb, stats + 256, stats + 384, NN);
  // GIN layer 2 (BN2 finalize+affine+relu fused into the gather)
  gin_agg_kernel<true><<<12500, 256, 0, stream>>>(xb, row_start, csr,
                                                  stats + 256, gga[1], gbe[1], xa);
  gemm_gin_kernel<false><<<1564, 256, 0, stream>>>(xa, ginWT + 2 * 16384, gb[2],
                                                   nullptr, nullptr, nullptr,
                                                   xb, stats + 512, stats + 640, NN);
  gemm_gin_kernel<true><<<1564, 256, 0, stream>>>(xb, ginWT + 3 * 16384, gb[3],
                                                  stats + 512, gga[2], gbe[2],
                                                  xa, stats + 768, stats + 896, NN);
  // xa holds pre-BN4 features; BN4 fused into set2set x reads

  // fused Set2Set v2: 2 graphs per block, 1024 threads, no grid-wide syncs
  set2set_kernel<<<128, 1024, 0, stream>>>(xa, gptr, stats + 768, gga[3], gbe[3],
                                           WT0, WTR, bc0, bcR, ebuf, linW, linb, out);
}

// Round 8
// 584.586 us; speedup vs baseline: 2.2308x; 1.1130x over previous
//
#include <hip/hip_runtime.h>
#include <math.h>

#define NN 50000
#define EE 800000
#define BBG 256
#define HHC 128
#define SEG_CAP 232  // LDS x-cache rows per graph
#define ESC 512      // per-graph e-cache entries in LDS
#define NBIN 196     // coarse bins of 256 nodes
#define NBLK 196     // blocks in K1/K3 (4096 edges each)

__device__ __forceinline__ float4 aff4(float4 v, float4 sc, float4 sh) {
  v.x = fmaxf(fmaf(v.x, sc.x, sh.x), 0.f);
  v.y = fmaxf(fmaf(v.y, sc.y, sh.y), 0.f);
  v.z = fmaxf(fmaf(v.z, sc.z, sh.z), 0.f);
  v.w = fmaxf(fmaf(v.w, sc.w, sh.w), 0.f);
  return v;
}
__device__ __forceinline__ void add4(float4& a, float4 b) {
  a.x += b.x; a.y += b.y; a.z += b.z; a.w += b.w;
}

// ---------------- utility ----------------

__global__ void zero4_kernel(float4* p, int n) {
  int i = blockIdx.x * 256 + threadIdx.x;
  if (i < n) p[i] = make_float4(0.f, 0.f, 0.f, 0.f);
}

// batch is sorted: gptr[g] = first index with batch >= g; gptr[256] = NN
__global__ void gptr_boundary_kernel(const int* __restrict__ batch, int* __restrict__ gptr) {
  int i = blockIdx.x * 256 + threadIdx.x;
  if (i >= NN) return;
  int b = batch[i];
  int prev = (i == 0) ? -1 : batch[i - 1];
  for (int g = prev + 1; g <= b; ++g) gptr[g] = i;
  if (i == NN - 1) {
    for (int g = b + 1; g <= BBG; ++g) gptr[g] = NN;
  }
}

// ---- atomic-free CSR build (two-level counting sort) ----

__global__ __launch_bounds__(256) void coarse_hist_kernel(const int* __restrict__ ei,
                                                          int* __restrict__ partial) {
  __shared__ int hist[NBIN];
  int tid = threadIdx.x, b = blockIdx.x;
  if (tid < NBIN) hist[tid] = 0;
  __syncthreads();
  const int4* dst4 = (const int4*)(ei + EE);
#pragma unroll
  for (int c = 0; c < 4; ++c) {
    int idx = b * 1024 + c * 256 + tid;
    if (idx < EE / 4) {
      int4 d = dst4[idx];
      atomicAdd(&hist[d.x >> 8], 1);
      atomicAdd(&hist[d.y >> 8], 1);
      atomicAdd(&hist[d.z >> 8], 1);
      atomicAdd(&hist[d.w >> 8], 1);
    }
  }
  __syncthreads();
  if (tid < NBIN) partial[tid * NBLK + b] = hist[tid];
}

__global__ void scan_partials_kernel(const int* __restrict__ partial,
                                     int* __restrict__ block_base, int* __restrict__ total) {
  __shared__ int buf[256];
  int bin = blockIdx.x, tid = threadIdx.x;
  int v = (tid < NBLK) ? partial[bin * NBLK + tid] : 0;
  buf[tid] = v;
  __syncthreads();
  for (int off = 1; off < 256; off <<= 1) {
    int t = (tid >= off) ? buf[tid - off] : 0;
    __syncthreads();
    buf[tid] += t;
    __syncthreads();
  }
  if (tid < NBLK) block_base[bin * NBLK + tid] = buf[tid] - v;
  if (tid == 255) total[bin] = buf[255];
}

__global__ void scan_totals_kernel(const int* __restrict__ total, int* __restrict__ coarse_base) {
  __shared__ int buf[256];
  int tid = threadIdx.x;
  int v = (tid < NBIN) ? total[tid] : 0;
  buf[tid] = v;
  __syncthreads();
  for (int off = 1; off < 256; off <<= 1) {
    int t = (tid >= off) ? buf[tid - off] : 0;
    __syncthreads();
    buf[tid] += t;
    __syncthreads();
  }
  if (tid < NBIN) coarse_base[tid] = buf[tid] - v;
  if (tid == 255) coarse_base[NBIN] = buf[255];
}

__global__ __launch_bounds__(256) void bucket_scatter_kernel(const int* __restrict__ ei,
                                                             const int* __restrict__ coarse_base,
                                                             const int* __restrict__ block_base,
                                                             int* __restrict__ packed) {
  __shared__ int cursor[NBIN];
  int tid = threadIdx.x, b = blockIdx.x;
  if (tid < NBIN) cursor[tid] = coarse_base[tid] + block_base[tid * NBLK + b];
  __syncthreads();
  const int4* src4 = (const int4*)ei;
  const int4* dst4 = (const int4*)(ei + EE);
#pragma unroll
  for (int c = 0; c < 4; ++c) {
    int idx = b * 1024 + c * 256 + tid;
    if (idx < EE / 4) {
      int4 s = src4[idx];
      int4 d = dst4[idx];
      int p;
      p = atomicAdd(&cursor[d.x >> 8], 1); packed[p] = (s.x << 8) | (d.x & 255);
      p = atomicAdd(&cursor[d.y >> 8], 1); packed[p] = (s.y << 8) | (d.y & 255);
      p = atomicAdd(&cursor[d.z >> 8], 1); packed[p] = (s.z << 8) | (d.z & 255);
      p = atomicAdd(&cursor[d.w >> 8], 1); packed[p] = (s.w << 8) | (d.w & 255);
    }
  }
}

__global__ __launch_bounds__(256) void csr_finalize_kernel(const int* __restrict__ packed,
                                                           const int* __restrict__ coarse_base,
                                                           int* __restrict__ row_start,
                                                           int* __restrict__ csr) {
  __shared__ int fh[256];
  __shared__ int fb[256];
  int bin = blockIdx.x, tid = threadIdx.x;
  int e0 = coarse_base[bin], e1 = coarse_base[bin + 1];
  fh[tid] = 0;
  __syncthreads();
  for (int e = e0 + tid; e < e1; e += 256) atomicAdd(&fh[packed[e] & 255], 1);
  __syncthreads();
  int v = fh[tid];
  fb[tid] = v;
  __syncthreads();
  for (int off = 1; off < 256; off <<= 1) {
    int t = (tid >= off) ? fb[tid - off] : 0;
    __syncthreads();
    fb[tid] += t;
    __syncthreads();
  }
  int excl = fb[tid] - v;
  int node = bin * 256 + tid;
  if (node < NN) row_start[node] = e0 + excl;
  if (bin == NBIN - 1 && tid == 0) row_start[NN] = EE;
  __syncthreads();
  fb[tid] = excl;  // cursor
  __syncthreads();
  for (int e = e0 + tid; e < e1; e += 256) {
    int p = packed[e];
    int pos = atomicAdd(&fb[p & 255], 1);
    csr[e0 + pos] = p >> 8;
  }
}

// ---------------- weight prep (single kernel) ----------------
__global__ void prep_weights_kernel(const float* __restrict__ W0, const float* __restrict__ W1,
                                    const float* __restrict__ W2, const float* __restrict__ W3,
                                    const float* __restrict__ Wih0, const float* __restrict__ Whh0,
                                    const float* __restrict__ WihR, const float* __restrict__ WhhR,
                                    const float* __restrict__ b0, const float* __restrict__ bR,
                                    float* __restrict__ ginWT, float* __restrict__ WT0,
                                    float* __restrict__ WTR, float* __restrict__ bc0,
                                    float* __restrict__ bcR) {
  int idx = blockIdx.x * 256 + threadIdx.x;  // grid 2568*256 = 657408 exact
  if (idx < 65536) {
    int m = idx >> 14;
    int r = idx & 16383;
    int k = r >> 7, o = r & 127;
    const float* W = (m == 0) ? W0 : (m == 1) ? W1 : (m == 2) ? W2 : W3;
    ginWT[idx] = W[o * 128 + k];
  } else if (idx < 262144) {
    int t = idx - 65536;
    int k = t >> 9, op = t & 511;
    int j = op >> 2, g = op & 3;
    int row = g * 128 + j;
    WT0[t] = (k < 256) ? Wih0[row * 256 + k] : Whh0[row * 128 + (k - 256)];
  } else if (idx < 655360) {
    int t = idx - 262144;
    int l = t >> 17;
    int rem = t & 131071;
    int k = rem >> 9, op = rem & 511;
    int j = op >> 2, g = op & 3;
    int row = g * 128 + j;
    WTR[t] = (k < 128) ? WihR[((size_t)l * 512 + row) * 128 + k]
                       : WhhR[((size_t)l * 512 + row) * 128 + (k - 128)];
  } else {
    int t = idx - 655360;
    if (t < 512) {
      bc0[t] = b0[(t & 3) * 128 + (t >> 2)];
    } else {
      int u = t - 512;
      int l = u >> 9, op = u & 511;
      bcR[u] = bR[l * 512 + (op & 3) * 128 + (op >> 2)];
    }
  }
}

// ---------------- GIN ----------------

// one wave per node; each 32-lane half loads a full 512B row as float4.
template <bool AFF>
__global__ __launch_bounds__(256) void gin_agg_kernel(
    const float* __restrict__ xin, const int* __restrict__ row_start,
    const int* __restrict__ csr,
    const float* __restrict__ stats, const float* __restrict__ gamma,
    const float* __restrict__ beta, float* __restrict__ outp) {
  __shared__ float sc_s[128], sh_s[128];
  if (AFF) {
    int t = threadIdx.x;
    if (t < 128) {
      const float invN = 1.0f / (float)NN;
      float mm = stats[t] * invN;
      float vv = stats[128 + t] * invN - mm * mm;
      float rs = rsqrtf(vv + 1e-5f);
      float sc = gamma[t] * rs;
      sc_s[t] = sc;
      sh_s[t] = beta[t] - mm * sc;
    }
    __syncthreads();
  }
  int node = blockIdx.x * 4 + (threadIdx.x >> 6);  // exact: 12500*4 = 50000
  int lane = threadIdx.x & 63;
  int half = lane >> 5, ln = lane & 31;
  const float4* x4 = (const float4*)xin;
  float4 sc4 = make_float4(0.f, 0.f, 0.f, 0.f), sh4 = sc4;
  if (AFF) {
    sc4 = *(const float4*)&sc_s[4 * ln];
    sh4 = *(const float4*)&sh_s[4 * ln];
  }
  int s0 = row_start[node], s1 = row_start[node + 1];
  float4 self = x4[(size_t)node * 32 + ln];
  if (AFF) self = aff4(self, sc4, sh4);
  float4 c0 = make_float4(0.f, 0.f, 0.f, 0.f), c1 = c0, c2 = c0, c3 = c0;
  int cnt = s1 - s0;
  int mainEnd = s0 + (cnt & ~15);
  for (int j = s0; j < mainEnd; j += 16) {
    int i0 = csr[j + half + 0];
    int i1 = csr[j + half + 2];
    int i2 = csr[j + half + 4];
    int i3 = csr[j + half + 6];
    int i4 = csr[j + half + 8];
    int i5 = csr[j + half + 10];
    int i6 = csr[j + half + 12];
    int i7 = csr[j + half + 14];
    float4 v0 = x4[(size_t)i0 * 32 + ln];
    float4 v1 = x4[(size_t)i1 * 32 + ln];
    float4 v2 = x4[(size_t)i2 * 32 + ln];
    float4 v3 = x4[(size_t)i3 * 32 + ln];
    float4 v4 = x4[(size_t)i4 * 32 + ln];
    float4 v5 = x4[(size_t)i5 * 32 + ln];
    float4 v6 = x4[(size_t)i6 * 32 + ln];
    float4 v7 = x4[(size_t)i7 * 32 + ln];
    if (AFF) {
      v0 = aff4(v0, sc4, sh4); v1 = aff4(v1, sc4, sh4);
      v2 = aff4(v2, sc4, sh4); v3 = aff4(v3, sc4, sh4);
      v4 = aff4(v4, sc4, sh4); v5 = aff4(v5, sc4, sh4);
      v6 = aff4(v6, sc4, sh4); v7 = aff4(v7, sc4, sh4);
    }
    add4(c0, v0); add4(c1, v1); add4(c2, v2); add4(c3, v3);
    add4(c0, v4); add4(c1, v5); add4(c2, v6); add4(c3, v7);
  }
  for (int j = mainEnd + half; j < s1; j += 2) {
    int i = csr[j];
    float4 v = x4[(size_t)i * 32 + ln];
    if (AFF) v = aff4(v, sc4, sh4);
    add4(c0, v);
  }
  float4 t;
  t.x = (c0.x + c1.x) + (c2.x + c3.x);
  t.y = (c0.y + c1.y) + (c2.y + c3.y);
  t.z = (c0.z + c1.z) + (c2.z + c3.z);
  t.w = (c0.w + c1.w) + (c2.w + c3.w);
  t.x += __shfl_xor(t.x, 32);
  t.y += __shfl_xor(t.y, 32);
  t.z += __shfl_xor(t.z, 32);
  t.w += __shfl_xor(t.w, 32);
  t.x += self.x; t.y += self.y; t.z += self.z; t.w += self.w;
  if (half == 0) ((float4*)outp)[(size_t)node * 32 + ln] = t;
}

// C = f(A) @ W^T + b, f = optional fused BN(stats)+relu; per-channel stats atomics.
template <bool BN>
__global__ __launch_bounds__(256) void gemm_gin_kernel(
    const float* __restrict__ A, const float* __restrict__ WT,
    const float* __restrict__ bias,
    const float* __restrict__ stats, const float* __restrict__ gamma,
    const float* __restrict__ beta,
    float* __restrict__ C,
    float* __restrict__ ssum, float* __restrict__ ssq, int M) {
  __shared__ float As[64][132];
  __shared__ float Wt[128][68];
  __shared__ float bsc[128], bsh[128];
  int tid = threadIdx.x;
  if (BN) {
    if (tid < 128) {
      const float invN = 1.0f / (float)NN;
      float mm = stats[tid] * invN;
      float vv = stats[128 + tid] * invN - mm * mm;
      float rs = rsqrtf(vv + 1e-5f);
      float sc = gamma[tid] * rs;
      bsc[tid] = sc;
      bsh[tid] = beta[tid] - mm * sc;
    }
    __syncthreads();
  }
  int tx = tid & 15, ty = tid >> 4;
  int bx = blockIdx.x & 1, by = blockIdx.x >> 1;
  int row0 = by * 64, c0 = bx * 64;
#pragma unroll
  for (int i = 0; i < 8; ++i) {
    int slot = tid + i * 256;
    int r = slot >> 5, k4 = (slot & 31) << 2;
    float4 v = make_float4(0.f, 0.f, 0.f, 0.f);
    if (row0 + r < M) v = *(const float4*)(A + (size_t)(row0 + r) * 128 + k4);
    if (BN) {
      v.x = fmaxf(fmaf(v.x, bsc[k4 + 0], bsh[k4 + 0]), 0.f);
      v.y = fmaxf(fmaf(v.y, bsc[k4 + 1], bsh[k4 + 1]), 0.f);
      v.z = fmaxf(fmaf(v.z, bsc[k4 + 2], bsh[k4 + 2]), 0.f);
      v.w = fmaxf(fmaf(v.w, bsc[k4 + 3], bsh[k4 + 3]), 0.f);
    }
    *(float4*)&As[r][k4] = v;
  }
#pragma unroll
  for (int i = 0; i < 8; ++i) {
    int slot = tid + i * 256;
    int k = slot >> 4, c4 = (slot & 15) << 2;
    *(float4*)&Wt[k][c4] = *(const float4*)(WT + (size_t)k * 128 + c0 + c4);
  }
  __syncthreads();
  float acc[4][4];
#pragma unroll
  for (int i = 0; i < 4; ++i)
#pragma unroll
    for (int j = 0; j < 4; ++j) acc[i][j] = 0.f;
#pragma unroll 4
  for (int kk = 0; kk < 128; kk += 4) {
    float4 w0 = *(const float4*)&Wt[kk + 0][tx << 2];
    float4 w1 = *(const float4*)&Wt[kk + 1][tx << 2];
    float4 w2 = *(const float4*)&Wt[kk + 2][tx << 2];
    float4 w3 = *(const float4*)&Wt[kk + 3][tx << 2];
#pragma unroll
    for (int i = 0; i < 4; ++i) {
      float4 a = *(const float4*)&As[(ty << 2) + i][kk];
      acc[i][0] += a.x * w0.x + a.y * w1.x + a.z * w2.x + a.w * w3.x;
      acc[i][1] += a.x * w0.y + a.y * w1.y + a.z * w2.y + a.w * w3.y;
      acc[i][2] += a.x * w0.z + a.y * w1.z + a.z * w2.z + a.w * w3.z;
      acc[i][3] += a.x * w0.w + a.y * w1.w + a.z * w2.w + a.w * w3.w;
    }
  }
  __syncthreads();
  float b0v = bias[c0 + (tx << 2) + 0];
  float b1v = bias[c0 + (tx << 2) + 1];
  float b2v = bias[c0 + (tx << 2) + 2];
  float b3v = bias[c0 + (tx << 2) + 3];
  float psum[4] = {0.f, 0.f, 0.f, 0.f}, psq[4] = {0.f, 0.f, 0.f, 0.f};
#pragma unroll
  for (int i = 0; i < 4; ++i) {
    int r = row0 + (ty << 2) + i;
    if (r < M) {
      float4 v;
      v.x = acc[i][0] + b0v; v.y = acc[i][1] + b1v;
      v.z = acc[i][2] + b2v; v.w = acc[i][3] + b3v;
      *(float4*)(C + (size_t)r * 128 + c0 + (tx << 2)) = v;
      psum[0] += v.x; psum[1] += v.y; psum[2] += v.z; psum[3] += v.w;
      psq[0] += v.x * v.x; psq[1] += v.y * v.y; psq[2] += v.z * v.z; psq[3] += v.w * v.w;
    }
  }
  float* red = &As[0][0];
#pragma unroll
  for (int j = 0; j < 4; ++j) {
    red[ty * 68 + (tx << 2) + j] = psum[j];
    red[1088 + ty * 68 + (tx << 2) + j] = psq[j];
  }
  __syncthreads();
  if (tid < 64) {
    float s = 0.f, sq = 0.f;
#pragma unroll
    for (int t = 0; t < 16; ++t) { s += red[t * 68 + tid]; sq += red[1088 + t * 68 + tid]; }
    atomicAdd(&ssum[c0 + tid], s);
    atomicAdd(&ssq[c0 + tid], sq);
  }
}

// ---------------- fused Set2Set v3: 1 graph/block, 1024 threads, LDS x-cache ---------
// x segment staged (BN4-applied) into LDS once; weights stream from L2 (2.3MB/XCD
// stays resident since x no longer pollutes L2). No grid-wide syncs.
__global__ void __launch_bounds__(1024) set2set_kernel(
    const float* __restrict__ x, const int* __restrict__ gptr,
    const float* __restrict__ stats, const float* __restrict__ gamma,
    const float* __restrict__ beta,
    const float* __restrict__ WT0, const float* __restrict__ WTR,
    const float* __restrict__ bc0, const float* __restrict__ bcR,
    float* __restrict__ ebuf,
    const float* __restrict__ linW, const float* __restrict__ linb,
    float* __restrict__ out) {
  __shared__ float xs[SEG_CAP * 128];  // 118784 B
  __shared__ float wpart[8][512];      // 16 KB
  __shared__ float inp_s[384];
  __shared__ float hcs[4][128];
  __shared__ float ccs[4][128];
  __shared__ float qst[256];
  __shared__ float es[ESC];            // 2 KB
  __shared__ float bsc[128], bsh[128];
  __shared__ float rpart[16][128];     // 8 KB
  __shared__ float wred[16];
  __shared__ float smax_s, ssum_s;
  __shared__ float fred[2][4];

  int g = blockIdx.x, tid = threadIdx.x;
  int w16 = tid >> 6, lane = tid & 63;

  // init
  if (tid < 128) {
    const float invN = 1.0f / (float)NN;
    float mm = stats[tid] * invN;
    float vv = stats[128 + tid] * invN - mm * mm;
    float rs = rsqrtf(vv + 1e-5f);
    float sc = gamma[tid] * rs;
    bsc[tid] = sc;
    bsh[tid] = beta[tid] - mm * sc;
#pragma unroll
    for (int l = 0; l < 4; ++l) { hcs[l][tid] = 0.f; ccs[l][tid] = 0.f; }
  }
  if (tid < 256) qst[tid] = 0.f;
  __syncthreads();

  int s0 = gptr[g], s1 = gptr[g + 1];
  int seg = s1 - s0;
  int ncache = seg < SEG_CAP ? seg : SEG_CAP;
  const float2* x2 = (const float2*)x;
  float sc0 = bsc[2 * lane], sc1 = bsc[2 * lane + 1];
  float sh0 = bsh[2 * lane], sh1 = bsh[2 * lane + 1];
  // stage segment into LDS once (BN4-transformed); one row per wave
  for (int n = w16; n < ncache; n += 16) {
    float2 v = x2[(size_t)(s0 + n) * 64 + lane];
    xs[n * 128 + 2 * lane] = fmaxf(fmaf(v.x, sc0, sh0), 0.f);
    xs[n * 128 + 2 * lane + 1] = fmaxf(fmaf(v.y, sc1, sh1), 0.f);
  }
  __syncthreads();

  int s_ = tid >> 7, cg = tid & 127;  // matvec role: K-slice, col-group

  for (int step = 0; step < 4; ++step) {
    // ---- 4 stacked LSTM cells ----
    for (int cell = 0; cell < 4; ++cell) {
      const float* WT; const float* bias; int K;
      if (cell == 0) {
        WT = WT0; bias = bc0; K = 384;
        if (tid < 256) inp_s[tid] = qst[tid];
        else if (tid < 384) inp_s[tid] = hcs[0][tid - 256];
      } else {
        WT = WTR + (size_t)(cell - 1) * 131072;
        bias = bcR + (cell - 1) * 512; K = 256;
        if (tid < 128) inp_s[tid] = hcs[cell - 1][tid];
        else if (tid < 256) inp_s[tid] = hcs[cell][tid - 128];
      }
      __syncthreads();
      int kper = K >> 3;
      int k0 = s_ * kper;
      const float* wp = WT + 4 * cg;
      float4 a0 = make_float4(0.f, 0.f, 0.f, 0.f);
      for (int k = k0; k < k0 + kper; k += 8) {
        float4 w0 = *(const float4*)(wp + (size_t)(k + 0) * 512);
        float4 w1 = *(const float4*)(wp + (size_t)(k + 1) * 512);
        float4 w2 = *(const float4*)(wp + (size_t)(k + 2) * 512);
        float4 w3 = *(const float4*)(wp + (size_t)(k + 3) * 512);
        float4 w4 = *(const float4*)(wp + (size_t)(k + 4) * 512);
        float4 w5 = *(const float4*)(wp + (size_t)(k + 5) * 512);
        float4 w6 = *(const float4*)(wp + (size_t)(k + 6) * 512);
        float4 w7 = *(const float4*)(wp + (size_t)(k + 7) * 512);
        float i0 = inp_s[k + 0], i1 = inp_s[k + 1], i2 = inp_s[k + 2], i3 = inp_s[k + 3];
        float i4 = inp_s[k + 4], i5 = inp_s[k + 5], i6 = inp_s[k + 6], i7 = inp_s[k + 7];
        a0.x += i0 * w0.x + i1 * w1.x + i2 * w2.x + i3 * w3.x;
        a0.y += i0 * w0.y + i1 * w1.y + i2 * w2.y + i3 * w3.y;
        a0.z += i0 * w0.z + i1 * w1.z + i2 * w2.z + i3 * w3.z;
        a0.w += i0 * w0.w + i1 * w1.w + i2 * w2.w + i3 * w3.w;
        a0.x += i4 * w4.x + i5 * w5.x + i6 * w6.x + i7 * w7.x;
        a0.y += i4 * w4.y + i5 * w5.y + i6 * w6.y + i7 * w7.y;
        a0.z += i4 * w4.z + i5 * w5.z + i6 * w6.z + i7 * w7.z;
        a0.w += i4 * w4.w + i5 * w5.w + i6 * w6.w + i7 * w7.w;
      }
      *(float4*)&wpart[s_][4 * cg] = a0;
      __syncthreads();
      if (tid < 128) {
        int j = tid;
        float gi = bias[4 * j + 0], gf = bias[4 * j + 1];
        float gc = bias[4 * j + 2], go = bias[4 * j + 3];
#pragma unroll
        for (int s = 0; s < 8; ++s) {
          gi += wpart[s][4 * j + 0];
          gf += wpart[s][4 * j + 1];
          gc += wpart[s][4 * j + 2];
          go += wpart[s][4 * j + 3];
        }
        float cp = ccs[cell][j];
        float si = 1.f / (1.f + expf(-gi));
        float sf = 1.f / (1.f + expf(-gf));
        float so = 1.f / (1.f + expf(-go));
        float cn = sf * cp + si * tanhf(gc);
        ccs[cell][j] = cn;
        hcs[cell][j] = so * tanhf(cn);
      }
      __syncthreads();
    }
    // ---- attention, q = new h[3]; x from LDS cache ----
    float qx = hcs[3][2 * lane], qy = hcs[3][2 * lane + 1];
    // pass 1: e + max
    float wmax = -3.0e38f;
    for (int n = w16; n < seg; n += 16) {
      float vx, vy;
      if (n < ncache) {
        vx = xs[n * 128 + 2 * lane];
        vy = xs[n * 128 + 2 * lane + 1];
      } else {
        float2 v = x2[(size_t)(s0 + n) * 64 + lane];
        vx = fmaxf(fmaf(v.x, sc0, sh0), 0.f);
        vy = fmaxf(fmaf(v.y, sc1, sh1), 0.f);
      }
      float e = vx * qx + vy * qy;
#pragma unroll
      for (int sh = 32; sh; sh >>= 1) e += __shfl_xor(e, sh);
      if (lane == 0) { if (n < ESC) es[n] = e; else ebuf[s0 + n] = e; }
      wmax = fmaxf(wmax, e);
    }
    if (lane == 0) wred[w16] = wmax;
    __syncthreads();
    if (tid == 0) {
      float m = wred[0];
#pragma unroll
      for (int t = 1; t < 16; ++t) m = fmaxf(m, wred[t]);
      smax_s = m;
    }
    __syncthreads();
    float m = smax_s;
    // pass 2: sum exp
    float loc = 0.f;
    for (int n = tid; n < seg; n += 1024) {
      float e = (n < ESC) ? es[n] : ebuf[s0 + n];
      loc += expf(e - m);
    }
#pragma unroll
    for (int sh = 32; sh; sh >>= 1) loc += __shfl_xor(loc, sh);
    __syncthreads();
    if (lane == 0) wred[w16] = loc;
    __syncthreads();
    if (tid == 0) {
      float s = 0.f;
#pragma unroll
      for (int t = 0; t < 16; ++t) s += wred[t];
      ssum_s = s;
    }
    __syncthreads();
    float inv = 1.0f / ssum_s;
    // pass 3: r = sum a*x
    float rx = 0.f, ry = 0.f;
    for (int n = w16; n < seg; n += 16) {
      float e = (n < ESC) ? es[n] : ebuf[s0 + n];
      float coef = expf(e - m) * inv;
      float vx, vy;
      if (n < ncache) {
        vx = xs[n * 128 + 2 * lane];
        vy = xs[n * 128 + 2 * lane + 1];
      } else {
        float2 v = x2[(size_t)(s0 + n) * 64 + lane];
        vx = fmaxf(fmaf(v.x, sc0, sh0), 0.f);
        vy = fmaxf(fmaf(v.y, sc1, sh1), 0.f);
      }
      rx += coef * vx; ry += coef * vy;
    }
    rpart[w16][2 * lane] = rx;
    rpart[w16][2 * lane + 1] = ry;
    __syncthreads();
    if (tid < 128) {
      float r = 0.f;
#pragma unroll
      for (int t = 0; t < 16; ++t) r += rpart[t][tid];
      qst[tid] = hcs[3][tid];
      qst[128 + tid] = r;
    }
    __syncthreads();
  }
  // ---- final linear ----
  if (tid < 256) {
    float val = qst[tid];
    float p0 = val * linW[tid];
    float p1 = val * linW[256 + tid];
#pragma unroll
    for (int sh = 32; sh; sh >>= 1) { p0 += __shfl_xor(p0, sh); p1 += __shfl_xor(p1, sh); }
    if (lane == 0) { fred[0][w16] = p0; fred[1][w16] = p1; }
  }
  __syncthreads();
  if (tid == 0) {
    out[2 * g + 0] = fred[0][0] + fred[0][1] + fred[0][2] + fred[0][3] + linb[0];
    out[2 * g + 1] = fred[1][0] + fred[1][1] + fred[1][2] + fred[1][3] + linb[1];
  }
}

// ---------------- launch ----------------

extern "C" void kernel_launch(void* const* d_in, const int* in_sizes, int n_in,
                              void* d_out, int out_size, void* d_ws, size_t ws_size,
                              hipStream_t stream) {
  const float* x = (const float*)d_in[0];
  const int* ei = (const int*)d_in[1];
  const int* batch = (const int*)d_in[2];
  const float* gW[4]  = {(const float*)d_in[3],  (const float*)d_in[7],
                         (const float*)d_in[11], (const float*)d_in[15]};
  const float* gb[4]  = {(const float*)d_in[4],  (const float*)d_in[8],
                         (const float*)d_in[12], (const float*)d_in[16]};
  const float* gga[4] = {(const float*)d_in[5],  (const float*)d_in[9],
                         (const float*)d_in[13], (const float*)d_in[17]};
  const float* gbe[4] = {(const float*)d_in[6],  (const float*)d_in[10],
                         (const float*)d_in[14], (const float*)d_in[18]};
  const float* Wih0 = (const float*)d_in[19];
  const float* Whh0 = (const float*)d_in[20];
  const float* b0   = (const float*)d_in[21];
  const float* WihR = (const float*)d_in[22];
  const float* WhhR = (const float*)d_in[23];
  const float* bR   = (const float*)d_in[24];
  const float* linW = (const float*)d_in[25];
  const float* linb = (const float*)d_in[26];
  float* out = (float*)d_out;

  char* base = (char*)d_ws;
  size_t off = 0;
  auto allocf = [&](size_t n) { float* p = (float*)(base + off); off += n * sizeof(float); return p; };
  float* xa    = allocf(6400000);
  float* xb    = allocf(6400000);
  float* ginWT = allocf(65536);
  float* WT0   = allocf(196608);
  float* WTR   = allocf(393216);
  float* bc0   = allocf(512);
  float* bcR   = allocf(1536);
  float* ebuf  = allocf(50000);
  // ---- zero region: stats only (1024 floats = 256 float4) ----
  float* stats = allocf(1024);     // 4 x (sum128|sq128)
  // ---- ints (all fully written before read; no zeroing needed) ----
  int* row_start = (int*)(base + off); off += 50004 * 4;
  int* gptr = (int*)(base + off); off += 260 * 4;
  int* csr = (int*)(base + off); off += 800000 * 4;
  int* packed = (int*)(base + off); off += 800000 * 4;
  int* partial = (int*)(base + off); off += NBIN * NBLK * 4;
  int* block_base = (int*)(base + off); off += NBIN * NBLK * 4;
  int* total = (int*)(base + off); off += 256 * 4;
  int* coarse_base = (int*)(base + off); off += 260 * 4;
  (void)ws_size; (void)in_sizes; (void)n_in; (void)out_size;

  // prep
  zero4_kernel<<<1, 256, 0, stream>>>((float4*)stats, 256);
  gptr_boundary_kernel<<<196, 256, 0, stream>>>(batch, gptr);
  coarse_hist_kernel<<<NBLK, 256, 0, stream>>>(ei, partial);
  scan_partials_kernel<<<NBIN, 256, 0, stream>>>(partial, block_base, total);
  scan_totals_kernel<<<1, 256, 0, stream>>>(total, coarse_base);
  bucket_scatter_kernel<<<NBLK, 256, 0, stream>>>(ei, coarse_base, block_base, packed);
  csr_finalize_kernel<<<NBIN, 256, 0, stream>>>(packed, coarse_base, row_start, csr);
  prep_weights_kernel<<<2568, 256, 0, stream>>>(gW[0], gW[1], gW[2], gW[3], Wih0, Whh0,
                                                WihR, WhhR, b0, bR, ginWT, WT0, WTR, bc0, bcR);

  // GIN layer 1
  gin_agg_kernel<false><<<12500, 256, 0, stream>>>(x, row_start, csr,
                                                   nullptr, nullptr, nullptr, xb);
  gemm_gin_kernel<false><<<1564, 256, 0, stream>>>(xb, ginWT + 0 * 16384, gb[0],
                                                   nullptr, nullptr, nullptr,
                                                   xa, stats + 0, stats + 128, NN);
  gemm_gin_kernel<true><<<1564, 256, 0, stream>>>(xa, ginWT + 1 * 16384, gb[1],
                                                  stats + 0, gga[0], gbe[0],
                                                  xb, stats + 256, stats + 384, NN);
  // GIN layer 2 (BN2 finalize+affine+relu fused into the gather)
  gin_agg_kernel<true><<<12500, 256, 0, stream>>>(xb, row_start, csr,
                                                  stats + 256, gga[1], gbe[1], xa);
  gemm_gin_kernel<false><<<1564, 256, 0, stream>>>(xa, ginWT + 2 * 16384, gb[2],
                                                   nullptr, nullptr, nullptr,
                                                   xb, stats + 512, stats + 640, NN);
  gemm_gin_kernel<true><<<1564, 256, 0, stream>>>(xb, ginWT + 3 * 16384, gb[3],
                                                  stats + 512, gga[2], gbe[2],
                                                  xa, stats + 768, stats + 896, NN);
  // xa holds pre-BN4 features; BN4 fused into set2set x staging

  // fused Set2Set v3: 1 graph/block, 1024 threads, LDS x-cache, no grid syncs
  set2set_kernel<<<256, 1024, 0, stream>>>(xa, gptr, stats + 768, gga[3], gbe[3],
                                           WT0, WTR, bc0, bcR, ebuf, linW, linb, out);
}

// Round 9
// 559.370 us; speedup vs baseline: 2.3314x; 1.0451x over previous
//
#include <hip/hip_runtime.h>
#include <math.h>

#define NN 50000
#define EE 800000
#define BBG 256
#define HHC 128
#define SEG_CAP 224  // LDS x-cache rows per graph
#define ESC 512      // per-graph e-cache entries in LDS
#define NBIN 196     // coarse bins of 256 nodes
#define NBLK 196     // blocks in K1/K3 (4096 edges each)

typedef _Float16 half8 __attribute__((ext_vector_type(8)));

__device__ __forceinline__ float4 aff4(float4 v, float4 sc, float4 sh) {
  v.x = fmaxf(fmaf(v.x, sc.x, sh.x), 0.f);
  v.y = fmaxf(fmaf(v.y, sc.y, sh.y), 0.f);
  v.z = fmaxf(fmaf(v.z, sc.z, sh.z), 0.f);
  v.w = fmaxf(fmaf(v.w, sc.w, sh.w), 0.f);
  return v;
}
__device__ __forceinline__ void add4(float4& a, float4 b) {
  a.x += b.x; a.y += b.y; a.z += b.z; a.w += b.w;
}

// ---------------- utility ----------------

__global__ void zero4_kernel(float4* p, int n) {
  int i = blockIdx.x * 256 + threadIdx.x;
  if (i < n) p[i] = make_float4(0.f, 0.f, 0.f, 0.f);
}

// batch is sorted: gptr[g] = first index with batch >= g; gptr[256] = NN
__global__ void gptr_boundary_kernel(const int* __restrict__ batch, int* __restrict__ gptr) {
  int i = blockIdx.x * 256 + threadIdx.x;
  if (i >= NN) return;
  int b = batch[i];
  int prev = (i == 0) ? -1 : batch[i - 1];
  for (int g = prev + 1; g <= b; ++g) gptr[g] = i;
  if (i == NN - 1) {
    for (int g = b + 1; g <= BBG; ++g) gptr[g] = NN;
  }
}

// ---- atomic-free CSR build (two-level counting sort) ----

__global__ __launch_bounds__(256) void coarse_hist_kernel(const int* __restrict__ ei,
                                                          int* __restrict__ partial) {
  __shared__ int hist[NBIN];
  int tid = threadIdx.x, b = blockIdx.x;
  if (tid < NBIN) hist[tid] = 0;
  __syncthreads();
  const int4* dst4 = (const int4*)(ei + EE);
#pragma unroll
  for (int c = 0; c < 4; ++c) {
    int idx = b * 1024 + c * 256 + tid;
    if (idx < EE / 4) {
      int4 d = dst4[idx];
      atomicAdd(&hist[d.x >> 8], 1);
      atomicAdd(&hist[d.y >> 8], 1);
      atomicAdd(&hist[d.z >> 8], 1);
      atomicAdd(&hist[d.w >> 8], 1);
    }
  }
  __syncthreads();
  if (tid < NBIN) partial[tid * NBLK + b] = hist[tid];
}

__global__ void scan_partials_kernel(const int* __restrict__ partial,
                                     int* __restrict__ block_base, int* __restrict__ total) {
  __shared__ int buf[256];
  int bin = blockIdx.x, tid = threadIdx.x;
  int v = (tid < NBLK) ? partial[bin * NBLK + tid] : 0;
  buf[tid] = v;
  __syncthreads();
  for (int off = 1; off < 256; off <<= 1) {
    int t = (tid >= off) ? buf[tid - off] : 0;
    __syncthreads();
    buf[tid] += t;
    __syncthreads();
  }
  if (tid < NBLK) block_base[bin * NBLK + tid] = buf[tid] - v;
  if (tid == 255) total[bin] = buf[255];
}

__global__ void scan_totals_kernel(const int* __restrict__ total, int* __restrict__ coarse_base) {
  __shared__ int buf[256];
  int tid = threadIdx.x;
  int v = (tid < NBIN) ? total[tid] : 0;
  buf[tid] = v;
  __syncthreads();
  for (int off = 1; off < 256; off <<= 1) {
    int t = (tid >= off) ? buf[tid - off] : 0;
    __syncthreads();
    buf[tid] += t;
    __syncthreads();
  }
  if (tid < NBIN) coarse_base[tid] = buf[tid] - v;
  if (tid == 255) coarse_base[NBIN] = buf[255];
}

__global__ __launch_bounds__(256) void bucket_scatter_kernel(const int* __restrict__ ei,
                                                             const int* __restrict__ coarse_base,
                                                             const int* __restrict__ block_base,
                                                             int* __restrict__ packed) {
  __shared__ int cursor[NBIN];
  int tid = threadIdx.x, b = blockIdx.x;
  if (tid < NBIN) cursor[tid] = coarse_base[tid] + block_base[tid * NBLK + b];
  __syncthreads();
  const int4* src4 = (const int4*)ei;
  const int4* dst4 = (const int4*)(ei + EE);
#pragma unroll
  for (int c = 0; c < 4; ++c) {
    int idx = b * 1024 + c * 256 + tid;
    if (idx < EE / 4) {
      int4 s = src4[idx];
      int4 d = dst4[idx];
      int p;
      p = atomicAdd(&cursor[d.x >> 8], 1); packed[p] = (s.x << 8) | (d.x & 255);
      p = atomicAdd(&cursor[d.y >> 8], 1); packed[p] = (s.y << 8) | (d.y & 255);
      p = atomicAdd(&cursor[d.z >> 8], 1); packed[p] = (s.z << 8) | (d.z & 255);
      p = atomicAdd(&cursor[d.w >> 8], 1); packed[p] = (s.w << 8) | (d.w & 255);
    }
  }
}

__global__ __launch_bounds__(256) void csr_finalize_kernel(const int* __restrict__ packed,
                                                           const int* __restrict__ coarse_base,
                                                           int* __restrict__ row_start,
                                                           int* __restrict__ csr) {
  __shared__ int fh[256];
  __shared__ int fb[256];
  int bin = blockIdx.x, tid = threadIdx.x;
  int e0 = coarse_base[bin], e1 = coarse_base[bin + 1];
  fh[tid] = 0;
  __syncthreads();
  for (int e = e0 + tid; e < e1; e += 256) atomicAdd(&fh[packed[e] & 255], 1);
  __syncthreads();
  int v = fh[tid];
  fb[tid] = v;
  __syncthreads();
  for (int off = 1; off < 256; off <<= 1) {
    int t = (tid >= off) ? fb[tid - off] : 0;
    __syncthreads();
    fb[tid] += t;
    __syncthreads();
  }
  int excl = fb[tid] - v;
  int node = bin * 256 + tid;
  if (node < NN) row_start[node] = e0 + excl;
  if (bin == NBIN - 1 && tid == 0) row_start[NN] = EE;
  __syncthreads();
  fb[tid] = excl;  // cursor
  __syncthreads();
  for (int e = e0 + tid; e < e1; e += 256) {
    int p = packed[e];
    int pos = atomicAdd(&fb[p & 255], 1);
    csr[e0 + pos] = p >> 8;
  }
}

// ---------------- weight prep (single kernel) ----------------
// LSTM weights emitted as fp16 (gate-interleaved col 4j+g); GIN weights fp32 k-major.
__global__ void prep_weights_kernel(const float* __restrict__ W0, const float* __restrict__ W1,
                                    const float* __restrict__ W2, const float* __restrict__ W3,
                                    const float* __restrict__ Wih0, const float* __restrict__ Whh0,
                                    const float* __restrict__ WihR, const float* __restrict__ WhhR,
                                    const float* __restrict__ b0, const float* __restrict__ bR,
                                    float* __restrict__ ginWT, _Float16* __restrict__ WT0h,
                                    _Float16* __restrict__ WTRh, float* __restrict__ bc0,
                                    float* __restrict__ bcR) {
  int idx = blockIdx.x * 256 + threadIdx.x;  // grid 2568*256 = 657408 exact
  if (idx < 65536) {
    int m = idx >> 14;
    int r = idx & 16383;
    int k = r >> 7, o = r & 127;
    const float* W = (m == 0) ? W0 : (m == 1) ? W1 : (m == 2) ? W2 : W3;
    ginWT[idx] = W[o * 128 + k];
  } else if (idx < 262144) {
    int t = idx - 65536;
    int k = t >> 9, op = t & 511;
    int j = op >> 2, g = op & 3;
    int row = g * 128 + j;
    float v = (k < 256) ? Wih0[row * 256 + k] : Whh0[row * 128 + (k - 256)];
    WT0h[t] = (_Float16)v;
  } else if (idx < 655360) {
    int t = idx - 262144;
    int l = t >> 17;
    int rem = t & 131071;
    int k = rem >> 9, op = rem & 511;
    int j = op >> 2, g = op & 3;
    int row = g * 128 + j;
    float v = (k < 128) ? WihR[((size_t)l * 512 + row) * 128 + k]
                        : WhhR[((size_t)l * 512 + row) * 128 + (k - 128)];
    WTRh[t] = (_Float16)v;
  } else {
    int t = idx - 655360;
    if (t < 512) {
      bc0[t] = b0[(t & 3) * 128 + (t >> 2)];
    } else {
      int u = t - 512;
      int l = u >> 9, op = u & 511;
      bcR[u] = bR[l * 512 + (op & 3) * 128 + (op >> 2)];
    }
  }
}

// ---------------- GIN ----------------

// one wave per node; each 32-lane half loads a full 512B row as float4.
template <bool AFF>
__global__ __launch_bounds__(256) void gin_agg_kernel(
    const float* __restrict__ xin, const int* __restrict__ row_start,
    const int* __restrict__ csr,
    const float* __restrict__ stats, const float* __restrict__ gamma,
    const float* __restrict__ beta, float* __restrict__ outp) {
  __shared__ float sc_s[128], sh_s[128];
  if (AFF) {
    int t = threadIdx.x;
    if (t < 128) {
      const float invN = 1.0f / (float)NN;
      float mm = stats[t] * invN;
      float vv = stats[128 + t] * invN - mm * mm;
      float rs = rsqrtf(vv + 1e-5f);
      float sc = gamma[t] * rs;
      sc_s[t] = sc;
      sh_s[t] = beta[t] - mm * sc;
    }
    __syncthreads();
  }
  int node = blockIdx.x * 4 + (threadIdx.x >> 6);  // exact: 12500*4 = 50000
  int lane = threadIdx.x & 63;
  int half = lane >> 5, ln = lane & 31;
  const float4* x4 = (const float4*)xin;
  float4 sc4 = make_float4(0.f, 0.f, 0.f, 0.f), sh4 = sc4;
  if (AFF) {
    sc4 = *(const float4*)&sc_s[4 * ln];
    sh4 = *(const float4*)&sh_s[4 * ln];
  }
  int s0 = row_start[node], s1 = row_start[node + 1];
  float4 self = x4[(size_t)node * 32 + ln];
  if (AFF) self = aff4(self, sc4, sh4);
  float4 c0 = make_float4(0.f, 0.f, 0.f, 0.f), c1 = c0, c2 = c0, c3 = c0;
  int cnt = s1 - s0;
  int mainEnd = s0 + (cnt & ~15);
  for (int j = s0; j < mainEnd; j += 16) {
    int i0 = csr[j + half + 0];
    int i1 = csr[j + half + 2];
    int i2 = csr[j + half + 4];
    int i3 = csr[j + half + 6];
    int i4 = csr[j + half + 8];
    int i5 = csr[j + half + 10];
    int i6 = csr[j + half + 12];
    int i7 = csr[j + half + 14];
    float4 v0 = x4[(size_t)i0 * 32 + ln];
    float4 v1 = x4[(size_t)i1 * 32 + ln];
    float4 v2 = x4[(size_t)i2 * 32 + ln];
    float4 v3 = x4[(size_t)i3 * 32 + ln];
    float4 v4 = x4[(size_t)i4 * 32 + ln];
    float4 v5 = x4[(size_t)i5 * 32 + ln];
    float4 v6 = x4[(size_t)i6 * 32 + ln];
    float4 v7 = x4[(size_t)i7 * 32 + ln];
    if (AFF) {
      v0 = aff4(v0, sc4, sh4); v1 = aff4(v1, sc4, sh4);
      v2 = aff4(v2, sc4, sh4); v3 = aff4(v3, sc4, sh4);
      v4 = aff4(v4, sc4, sh4); v5 = aff4(v5, sc4, sh4);
      v6 = aff4(v6, sc4, sh4); v7 = aff4(v7, sc4, sh4);
    }
    add4(c0, v0); add4(c1, v1); add4(c2, v2); add4(c3, v3);
    add4(c0, v4); add4(c1, v5); add4(c2, v6); add4(c3, v7);
  }
  for (int j = mainEnd + half; j < s1; j += 2) {
    int i = csr[j];
    float4 v = x4[(size_t)i * 32 + ln];
    if (AFF) v = aff4(v, sc4, sh4);
    add4(c0, v);
  }
  float4 t;
  t.x = (c0.x + c1.x) + (c2.x + c3.x);
  t.y = (c0.y + c1.y) + (c2.y + c3.y);
  t.z = (c0.z + c1.z) + (c2.z + c3.z);
  t.w = (c0.w + c1.w) + (c2.w + c3.w);
  t.x += __shfl_xor(t.x, 32);
  t.y += __shfl_xor(t.y, 32);
  t.z += __shfl_xor(t.z, 32);
  t.w += __shfl_xor(t.w, 32);
  t.x += self.x; t.y += self.y; t.z += self.z; t.w += self.w;
  if (half == 0) ((float4*)outp)[(size_t)node * 32 + ln] = t;
}

// C = f(A) @ W^T + b, f = optional fused BN(stats)+relu; per-channel stats atomics.
template <bool BN>
__global__ __launch_bounds__(256) void gemm_gin_kernel(
    const float* __restrict__ A, const float* __restrict__ WT,
    const float* __restrict__ bias,
    const float* __restrict__ stats, const float* __restrict__ gamma,
    const float* __restrict__ beta,
    float* __restrict__ C,
    float* __restrict__ ssum, float* __restrict__ ssq, int M) {
  __shared__ float As[64][132];
  __shared__ float Wt[128][68];
  __shared__ float bsc[128], bsh[128];
  int tid = threadIdx.x;
  if (BN) {
    if (tid < 128) {
      const float invN = 1.0f / (float)NN;
      float mm = stats[tid] * invN;
      float vv = stats[128 + tid] * invN - mm * mm;
      float rs = rsqrtf(vv + 1e-5f);
      float sc = gamma[tid] * rs;
      bsc[tid] = sc;
      bsh[tid] = beta[tid] - mm * sc;
    }
    __syncthreads();
  }
  int tx = tid & 15, ty = tid >> 4;
  int bx = blockIdx.x & 1, by = blockIdx.x >> 1;
  int row0 = by * 64, c0 = bx * 64;
#pragma unroll
  for (int i = 0; i < 8; ++i) {
    int slot = tid + i * 256;
    int r = slot >> 5, k4 = (slot & 31) << 2;
    float4 v = make_float4(0.f, 0.f, 0.f, 0.f);
    if (row0 + r < M) v = *(const float4*)(A + (size_t)(row0 + r) * 128 + k4);
    if (BN) {
      v.x = fmaxf(fmaf(v.x, bsc[k4 + 0], bsh[k4 + 0]), 0.f);
      v.y = fmaxf(fmaf(v.y, bsc[k4 + 1], bsh[k4 + 1]), 0.f);
      v.z = fmaxf(fmaf(v.z, bsc[k4 + 2], bsh[k4 + 2]), 0.f);
      v.w = fmaxf(fmaf(v.w, bsc[k4 + 3], bsh[k4 + 3]), 0.f);
    }
    *(float4*)&As[r][k4] = v;
  }
#pragma unroll
  for (int i = 0; i < 8; ++i) {
    int slot = tid + i * 256;
    int k = slot >> 4, c4 = (slot & 15) << 2;
    *(float4*)&Wt[k][c4] = *(const float4*)(WT + (size_t)k * 128 + c0 + c4);
  }
  __syncthreads();
  float acc[4][4];
#pragma unroll
  for (int i = 0; i < 4; ++i)
#pragma unroll
    for (int j = 0; j < 4; ++j) acc[i][j] = 0.f;
#pragma unroll 4
  for (int kk = 0; kk < 128; kk += 4) {
    float4 w0 = *(const float4*)&Wt[kk + 0][tx << 2];
    float4 w1 = *(const float4*)&Wt[kk + 1][tx << 2];
    float4 w2 = *(const float4*)&Wt[kk + 2][tx << 2];
    float4 w3 = *(const float4*)&Wt[kk + 3][tx << 2];
#pragma unroll
    for (int i = 0; i < 4; ++i) {
      float4 a = *(const float4*)&As[(ty << 2) + i][kk];
      acc[i][0] += a.x * w0.x + a.y * w1.x + a.z * w2.x + a.w * w3.x;
      acc[i][1] += a.x * w0.y + a.y * w1.y + a.z * w2.y + a.w * w3.y;
      acc[i][2] += a.x * w0.z + a.y * w1.z + a.z * w2.z + a.w * w3.z;
      acc[i][3] += a.x * w0.w + a.y * w1.w + a.z * w2.w + a.w * w3.w;
    }
  }
  __syncthreads();
  float b0v = bias[c0 + (tx << 2) + 0];
  float b1v = bias[c0 + (tx << 2) + 1];
  float b2v = bias[c0 + (tx << 2) + 2];
  float b3v = bias[c0 + (tx << 2) + 3];
  float psum[4] = {0.f, 0.f, 0.f, 0.f}, psq[4] = {0.f, 0.f, 0.f, 0.f};
#pragma unroll
  for (int i = 0; i < 4; ++i) {
    int r = row0 + (ty << 2) + i;
    if (r < M) {
      float4 v;
      v.x = acc[i][0] + b0v; v.y = acc[i][1] + b1v;
      v.z = acc[i][2] + b2v; v.w = acc[i][3] + b3v;
      *(float4*)(C + (size_t)r * 128 + c0 + (tx << 2)) = v;
      psum[0] += v.x; psum[1] += v.y; psum[2] += v.z; psum[3] += v.w;
      psq[0] += v.x * v.x; psq[1] += v.y * v.y; psq[2] += v.z * v.z; psq[3] += v.w * v.w;
    }
  }
  float* red = &As[0][0];
#pragma unroll
  for (int j = 0; j < 4; ++j) {
    red[ty * 68 + (tx << 2) + j] = psum[j];
    red[1088 + ty * 68 + (tx << 2) + j] = psq[j];
  }
  __syncthreads();
  if (tid < 64) {
    float s = 0.f, sq = 0.f;
#pragma unroll
    for (int t = 0; t < 16; ++t) { s += red[t * 68 + tid]; sq += red[1088 + t * 68 + tid]; }
    atomicAdd(&ssum[c0 + tid], s);
    atomicAdd(&ssq[c0 + tid], sq);
  }
}

// ---------------- fused Set2Set v4: fp16 weights, 1 graph/block, LDS x-cache ---------
// Mat-vec: 16 K-slices x 64 col-groups (8 cols each); half8 (16B) coalesced loads.
// Slice start rotated per block to de-hot-bank L2. Gate reduce across 512 threads.
__global__ void __launch_bounds__(1024) set2set_kernel(
    const float* __restrict__ x, const int* __restrict__ gptr,
    const float* __restrict__ stats, const float* __restrict__ gamma,
    const float* __restrict__ beta,
    const _Float16* __restrict__ WT0h, const _Float16* __restrict__ WTRh,
    const float* __restrict__ bc0, const float* __restrict__ bcR,
    float* __restrict__ ebuf,
    const float* __restrict__ linW, const float* __restrict__ linb,
    float* __restrict__ out) {
  __shared__ float xs[SEG_CAP * 128];  // 114688 B
  __shared__ float wpart[16][512];     // 32 KB (aliased as rpart in attention)
  __shared__ float gates[512];
  __shared__ float inp_s[384];
  __shared__ float hcs[4][128];
  __shared__ float ccs[4][128];
  __shared__ float qst[256];
  __shared__ float es[ESC];            // 2 KB
  __shared__ float bsc[128], bsh[128];
  __shared__ float wred[16];
  __shared__ float smax_s, ssum_s;
  __shared__ float fred[2][4];

  int g = blockIdx.x, tid = threadIdx.x;
  int w16 = tid >> 6, lane = tid & 63;

  // init
  if (tid < 128) {
    const float invN = 1.0f / (float)NN;
    float mm = stats[tid] * invN;
    float vv = stats[128 + tid] * invN - mm * mm;
    float rs = rsqrtf(vv + 1e-5f);
    float sc = gamma[tid] * rs;
    bsc[tid] = sc;
    bsh[tid] = beta[tid] - mm * sc;
#pragma unroll
    for (int l = 0; l < 4; ++l) { hcs[l][tid] = 0.f; ccs[l][tid] = 0.f; }
  }
  if (tid < 256) qst[tid] = 0.f;
  __syncthreads();

  int s0 = gptr[g], s1 = gptr[g + 1];
  int seg = s1 - s0;
  int ncache = seg < SEG_CAP ? seg : SEG_CAP;
  const float2* x2 = (const float2*)x;
  float sc0 = bsc[2 * lane], sc1 = bsc[2 * lane + 1];
  float sh0 = bsh[2 * lane], sh1 = bsh[2 * lane + 1];
  // stage segment into LDS once (BN4-transformed); one row per wave
  for (int n = w16; n < ncache; n += 16) {
    float2 v = x2[(size_t)(s0 + n) * 64 + lane];
    xs[n * 128 + 2 * lane] = fmaxf(fmaf(v.x, sc0, sh0), 0.f);
    xs[n * 128 + 2 * lane + 1] = fmaxf(fmaf(v.y, sc1, sh1), 0.f);
  }
  __syncthreads();

  int s_ = tid >> 6, cg = tid & 63;  // matvec: K-slice (16), col-group (8 cols)

  for (int step = 0; step < 4; ++step) {
    // ---- 4 stacked LSTM cells ----
    for (int cell = 0; cell < 4; ++cell) {
      const _Float16* WTh; const float* bias; int K;
      if (cell == 0) {
        WTh = WT0h; bias = bc0; K = 384;
        if (tid < 256) inp_s[tid] = qst[tid];
        else if (tid < 384) inp_s[tid] = hcs[0][tid - 256];
      } else {
        WTh = WTRh + (size_t)(cell - 1) * 131072;
        bias = bcR + (cell - 1) * 512; K = 256;
        if (tid < 128) inp_s[tid] = hcs[cell - 1][tid];
        else if (tid < 256) inp_s[tid] = hcs[cell][tid - 128];
      }
      __syncthreads();
      int kper = K >> 4;
      int se = (s_ + g) & 15;           // rotate slice start per block
      int k0 = se * kper;
      const _Float16* wp = WTh + 8 * cg;
      float a[8] = {0.f, 0.f, 0.f, 0.f, 0.f, 0.f, 0.f, 0.f};
      for (int k = k0; k < k0 + kper; k += 8) {
        half8 w0 = *(const half8*)(wp + (size_t)(k + 0) * 512);
        half8 w1 = *(const half8*)(wp + (size_t)(k + 1) * 512);
        half8 w2 = *(const half8*)(wp + (size_t)(k + 2) * 512);
        half8 w3 = *(const half8*)(wp + (size_t)(k + 3) * 512);
        half8 w4 = *(const half8*)(wp + (size_t)(k + 4) * 512);
        half8 w5 = *(const half8*)(wp + (size_t)(k + 5) * 512);
        half8 w6 = *(const half8*)(wp + (size_t)(k + 6) * 512);
        half8 w7 = *(const half8*)(wp + (size_t)(k + 7) * 512);
        float i0 = inp_s[k + 0], i1 = inp_s[k + 1], i2 = inp_s[k + 2], i3 = inp_s[k + 3];
        float i4 = inp_s[k + 4], i5 = inp_s[k + 5], i6 = inp_s[k + 6], i7 = inp_s[k + 7];
#pragma unroll
        for (int j = 0; j < 8; ++j) {
          a[j] += i0 * (float)w0[j] + i1 * (float)w1[j] +
                  i2 * (float)w2[j] + i3 * (float)w3[j];
          a[j] += i4 * (float)w4[j] + i5 * (float)w5[j] +
                  i6 * (float)w6[j] + i7 * (float)w7[j];
        }
      }
#pragma unroll
      for (int j = 0; j < 8; ++j) wpart[s_][8 * cg + j] = a[j];
      __syncthreads();
      if (tid < 512) {
        float acc = bias[tid];
#pragma unroll
        for (int s = 0; s < 16; ++s) acc += wpart[s][tid];
        gates[tid] = acc;
      }
      __syncthreads();
      if (tid < 128) {
        int j = tid;
        float gi = gates[4 * j + 0];
        float gf = gates[4 * j + 1];
        float gc = gates[4 * j + 2];
        float go = gates[4 * j + 3];
        float cp = ccs[cell][j];
        float si = 1.f / (1.f + expf(-gi));
        float sf = 1.f / (1.f + expf(-gf));
        float so = 1.f / (1.f + expf(-go));
        float cn = sf * cp + si * tanhf(gc);
        ccs[cell][j] = cn;
        hcs[cell][j] = so * tanhf(cn);
      }
      __syncthreads();
    }
    // ---- attention, q = new h[3]; x from LDS cache ----
    float* rpart = &wpart[0][0];  // alias: time-disjoint with matvec
    float qx = hcs[3][2 * lane], qy = hcs[3][2 * lane + 1];
    // pass 1: e + max
    float wmax = -3.0e38f;
    for (int n = w16; n < seg; n += 16) {
      float vx, vy;
      if (n < ncache) {
        vx = xs[n * 128 + 2 * lane];
        vy = xs[n * 128 + 2 * lane + 1];
      } else {
        float2 v = x2[(size_t)(s0 + n) * 64 + lane];
        vx = fmaxf(fmaf(v.x, sc0, sh0), 0.f);
        vy = fmaxf(fmaf(v.y, sc1, sh1), 0.f);
      }
      float e = vx * qx + vy * qy;
#pragma unroll
      for (int sh = 32; sh; sh >>= 1) e += __shfl_xor(e, sh);
      if (lane == 0) { if (n < ESC) es[n] = e; else ebuf[s0 + n] = e; }
      wmax = fmaxf(wmax, e);
    }
    if (lane == 0) wred[w16] = wmax;
    __syncthreads();
    if (tid == 0) {
      float m = wred[0];
#pragma unroll
      for (int t = 1; t < 16; ++t) m = fmaxf(m, wred[t]);
      smax_s = m;
    }
    __syncthreads();
    float m = smax_s;
    // pass 2: sum exp
    float loc = 0.f;
    for (int n = tid; n < seg; n += 1024) {
      float e = (n < ESC) ? es[n] : ebuf[s0 + n];
      loc += expf(e - m);
    }
#pragma unroll
    for (int sh = 32; sh; sh >>= 1) loc += __shfl_xor(loc, sh);
    __syncthreads();
    if (lane == 0) wred[w16] = loc;
    __syncthreads();
    if (tid == 0) {
      float s = 0.f;
#pragma unroll
      for (int t = 0; t < 16; ++t) s += wred[t];
      ssum_s = s;
    }
    __syncthreads();
    float inv = 1.0f / ssum_s;
    // pass 3: r = sum a*x
    float rx = 0.f, ry = 0.f;
    for (int n = w16; n < seg; n += 16) {
      float e = (n < ESC) ? es[n] : ebuf[s0 + n];
      float coef = expf(e - m) * inv;
      float vx, vy;
      if (n < ncache) {
        vx = xs[n * 128 + 2 * lane];
        vy = xs[n * 128 + 2 * lane + 1];
      } else {
        float2 v = x2[(size_t)(s0 + n) * 64 + lane];
        vx = fmaxf(fmaf(v.x, sc0, sh0), 0.f);
        vy = fmaxf(fmaf(v.y, sc1, sh1), 0.f);
      }
      rx += coef * vx; ry += coef * vy;
    }
    rpart[w16 * 128 + 2 * lane] = rx;
    rpart[w16 * 128 + 2 * lane + 1] = ry;
    __syncthreads();
    if (tid < 128) {
      float r = 0.f;
#pragma unroll
      for (int t = 0; t < 16; ++t) r += rpart[t * 128 + tid];
      qst[tid] = hcs[3][tid];
      qst[128 + tid] = r;
    }
    __syncthreads();
  }
  // ---- final linear ----
  if (tid < 256) {
    float val = qst[tid];
    float p0 = val * linW[tid];
    float p1 = val * linW[256 + tid];
#pragma unroll
    for (int sh = 32; sh; sh >>= 1) { p0 += __shfl_xor(p0, sh); p1 += __shfl_xor(p1, sh); }
    if (lane == 0) { fred[0][w16] = p0; fred[1][w16] = p1; }
  }
  __syncthreads();
  if (tid == 0) {
    out[2 * g + 0] = fred[0][0] + fred[0][1] + fred[0][2] + fred[0][3] + linb[0];
    out[2 * g + 1] = fred[1][0] + fred[1][1] + fred[1][2] + fred[1][3] + linb[1];
  }
}

// ---------------- launch ----------------

extern "C" void kernel_launch(void* const* d_in, const int* in_sizes, int n_in,
                              void* d_out, int out_size, void* d_ws, size_t ws_size,
                              hipStream_t stream) {
  const float* x = (const float*)d_in[0];
  const int* ei = (const int*)d_in[1];
  const int* batch = (const int*)d_in[2];
  const float* gW[4]  = {(const float*)d_in[3],  (const float*)d_in[7],
                         (const float*)d_in[11], (const float*)d_in[15]};
  const float* gb[4]  = {(const float*)d_in[4],  (const float*)d_in[8],
                         (const float*)d_in[12], (const float*)d_in[16]};
  const float* gga[4] = {(const float*)d_in[5],  (const float*)d_in[9],
                         (const float*)d_in[13], (const float*)d_in[17]};
  const float* gbe[4] = {(const float*)d_in[6],  (const float*)d_in[10],
                         (const float*)d_in[14], (const float*)d_in[18]};
  const float* Wih0 = (const float*)d_in[19];
  const float* Whh0 = (const float*)d_in[20];
  const float* b0   = (const float*)d_in[21];
  const float* WihR = (const float*)d_in[22];
  const float* WhhR = (const float*)d_in[23];
  const float* bR   = (const float*)d_in[24];
  const float* linW = (const float*)d_in[25];
  const float* linb = (const float*)d_in[26];
  float* out = (float*)d_out;

  char* base = (char*)d_ws;
  size_t off = 0;
  auto allocf = [&](size_t n) { float* p = (float*)(base + off); off += n * sizeof(float); return p; };
  float* xa    = allocf(6400000);
  float* xb    = allocf(6400000);
  float* ginWT = allocf(65536);
  _Float16* WT0h = (_Float16*)(base + off); off += 196608 * 2;
  _Float16* WTRh = (_Float16*)(base + off); off += 393216 * 2;
  float* bc0   = allocf(512);
  float* bcR   = allocf(1536);
  float* ebuf  = allocf(50000);
  // ---- zero region: stats only (1024 floats = 256 float4) ----
  float* stats = allocf(1024);     // 4 x (sum128|sq128)
  // ---- ints (all fully written before read; no zeroing needed) ----
  int* row_start = (int*)(base + off); off += 50004 * 4;
  int* gptr = (int*)(base + off); off += 260 * 4;
  int* csr = (int*)(base + off); off += 800000 * 4;
  int* packed = (int*)(base + off); off += 800000 * 4;
  int* partial = (int*)(base + off); off += NBIN * NBLK * 4;
  int* block_base = (int*)(base + off); off += NBIN * NBLK * 4;
  int* total = (int*)(base + off); off += 256 * 4;
  int* coarse_base = (int*)(base + off); off += 260 * 4;
  (void)ws_size; (void)in_sizes; (void)n_in; (void)out_size;

  // prep
  zero4_kernel<<<1, 256, 0, stream>>>((float4*)stats, 256);
  gptr_boundary_kernel<<<196, 256, 0, stream>>>(batch, gptr);
  coarse_hist_kernel<<<NBLK, 256, 0, stream>>>(ei, partial);
  scan_partials_kernel<<<NBIN, 256, 0, stream>>>(partial, block_base, total);
  scan_totals_kernel<<<1, 256, 0, stream>>>(total, coarse_base);
  bucket_scatter_kernel<<<NBLK, 256, 0, stream>>>(ei, coarse_base, block_base, packed);
  csr_finalize_kernel<<<NBIN, 256, 0, stream>>>(packed, coarse_base, row_start, csr);
  prep_weights_kernel<<<2568, 256, 0, stream>>>(gW[0], gW[1], gW[2], gW[3], Wih0, Whh0,
                                                WihR, WhhR, b0, bR, ginWT, WT0h, WTRh, bc0, bcR);

  // GIN layer 1
  gin_agg_kernel<false><<<12500, 256, 0, stream>>>(x, row_start, csr,
                                                   nullptr, nullptr, nullptr, xb);
  gemm_gin_kernel<false><<<1564, 256, 0, stream>>>(xb, ginWT + 0 * 16384, gb[0],
                                                   nullptr, nullptr, nullptr,
                                                   xa, stats + 0, stats + 128, NN);
  gemm_gin_kernel<true><<<1564, 256, 0, stream>>>(xa, ginWT + 1 * 16384, gb[1],
                                                  stats + 0, gga[0], gbe[0],
                                                  xb, stats + 256, stats + 384, NN);
  // GIN layer 2 (BN2 finalize+affine+relu fused into the gather)
  gin_agg_kernel<true><<<12500, 256, 0, stream>>>(xb, row_start, csr,
                                                  stats + 256, gga[1], gbe[1], xa);
  gemm_gin_kernel<false><<<1564, 256, 0, stream>>>(xa, ginWT + 2 * 16384, gb[2],
                                                   nullptr, nullptr, nullptr,
                                                   xb, stats + 512, stats + 640, NN);
  gemm_gin_kernel<true><<<1564, 256, 0, stream>>>(xb, ginWT + 3 * 16384, gb[3],
                                                  stats + 512, gga[2], gbe[2],
                                                  xa, stats + 768, stats + 896, NN);
  // xa holds pre-BN4 features; BN4 fused into set2set x staging

  // fused Set2Set v4: fp16 weights, 1 graph/block, LDS x-cache, no grid syncs
  set2set_kernel<<<256, 1024, 0, stream>>>(xa, gptr, stats + 768, gga[3], gbe[3],
                                           WT0h, WTRh, bc0, bcR, ebuf, linW, linb, out);
}